// Round 1
// baseline (209.816 us; speedup 1.0000x reference)
//
#include <hip/hip_runtime.h>

// ---------------------------------------------------------------------------
// DagLinkExtractor: B=8, N=1024, HID=1024, NH=4, HD=256
// out[b,i,j] = logsumexp_h( s_masked[b,i,j,h] + c[b,i,h] )
//   s = (Q_h . K_h)/16  (1/16 folded into stored Q)
//   c[b,i,h] = log_gate[b,i,h] - log(sum_{valid j} exp(s))
//   masked / dead-row positions -> exactly -1e9f
// ---------------------------------------------------------------------------

typedef __attribute__((ext_vector_type(8))) short bf16x8;
typedef __attribute__((ext_vector_type(4))) float f32x4;

#define LB __launch_bounds__(256)

__device__ __forceinline__ short f2bf(float f) {
    unsigned u = __float_as_uint(f);
    u += 0x7fffu + ((u >> 16) & 1u);   // RNE
    return (short)(u >> 16);
}

__device__ __forceinline__ void gld16(const void* g, void* l) {
    __builtin_amdgcn_global_load_lds(
        (const __attribute__((address_space(1))) unsigned int*)g,
        (__attribute__((address_space(3))) unsigned int*)l, 16, 0, 0);
}

// ---- 1. features f32 -> bf16 ------------------------------------------------
__global__ LB void k_cvt_x(const float* __restrict__ src, short* __restrict__ dst) {
    int idx = blockIdx.x * 256 + threadIdx.x;          // 1,048,576 threads * 8 elems
    const float4* s4 = (const float4*)src;
    float4 a = s4[idx * 2], b = s4[idx * 2 + 1];
    bf16x8 o;
    o[0] = f2bf(a.x); o[1] = f2bf(a.y); o[2] = f2bf(a.z); o[3] = f2bf(a.w);
    o[4] = f2bf(b.x); o[5] = f2bf(b.y); o[6] = f2bf(b.z); o[7] = f2bf(b.w);
    *(bf16x8*)&dst[idx * 8] = o;
}

// ---- 2. Wt[n][k] = W[k][n] (bf16), n<1024 -> Wq, else Wk --------------------
__global__ LB void k_cvt_w(const float* __restrict__ Wq, const float* __restrict__ Wk,
                           short* __restrict__ Wt) {
    __shared__ float tile[32][33];
    int n0 = blockIdx.x * 32, k0 = blockIdx.y * 32;
    const float* W = (n0 < 1024) ? Wq : Wk;
    int nb = n0 & 1023;
    int tx = threadIdx.x, ty = threadIdx.y;
#pragma unroll
    for (int jj = 0; jj < 4; ++jj) {
        int k = ty + jj * 8;
        tile[k][tx] = W[(size_t)(k0 + k) * 1024 + nb + tx];
    }
    __syncthreads();
#pragma unroll
    for (int jj = 0; jj < 4; ++jj) {
        int n = ty + jj * 8;
        Wt[(size_t)(n0 + n) * 1024 + k0 + tx] = f2bf(tile[tx][n]);
    }
}

// ---- 3. log_gates[b,i,h] ----------------------------------------------------
__global__ LB void k_gates(const float* __restrict__ feat, const float* __restrict__ Wg,
                           const float* __restrict__ bg, float* __restrict__ lgA) {
    int row = blockIdx.x * 4 + (threadIdx.x >> 6);     // 8192 rows, 1 wave each
    int lane = threadIdx.x & 63;
    const float* f = feat + (size_t)row * 1024;
    float g0 = 0.f, g1 = 0.f, g2 = 0.f, g3 = 0.f;
#pragma unroll
    for (int t = 0; t < 16; ++t) {
        int k = lane + t * 64;
        float x = f[k];
        float4 w = *(const float4*)&Wg[k * 4];
        g0 += x * w.x; g1 += x * w.y; g2 += x * w.z; g3 += x * w.w;
    }
#pragma unroll
    for (int off = 32; off; off >>= 1) {
        g0 += __shfl_xor(g0, off); g1 += __shfl_xor(g1, off);
        g2 += __shfl_xor(g2, off); g3 += __shfl_xor(g3, off);
    }
    g0 += bg[0]; g1 += bg[1]; g2 += bg[2]; g3 += bg[3];
    float m = fmaxf(fmaxf(g0, g1), fmaxf(g2, g3));
    float s = __expf(g0 - m) + __expf(g1 - m) + __expf(g2 - m) + __expf(g3 - m);
    float ls = m + __logf(s);
    if (lane == 0) {
        float4 o = {g0 - ls, g1 - ls, g2 - ls, g3 - ls};
        *(float4*)&lgA[row * 4] = o;
    }
}

// ---- 4. GEMM: Q = X@Wq+bq (scaled 1/16), K = X@Wk+bk; bf16 out, head layout -
__global__ LB void k_gemm(const short* __restrict__ Xb, const short* __restrict__ Wt,
                          const float* __restrict__ bq, const float* __restrict__ bk,
                          short* __restrict__ Qb, short* __restrict__ Kb) {
    __shared__ short Alds[128 * 32];
    __shared__ short Blds[128 * 32];
    const int t = threadIdx.x;
    const int lane = t & 63, wid = t >> 6;
    const int wm = wid >> 1, wn = wid & 1;
    const int m0 = (blockIdx.x >> 4) * 128, n0 = (blockIdx.x & 15) * 128;
    const int lr = lane & 15, lg4 = lane >> 4;
    f32x4 acc[4][4] = {};
    for (int k0 = 0; k0 < 1024; k0 += 32) {
        __syncthreads();
#pragma unroll
        for (int it = 0; it < 2; ++it) {
            int s = it * 256 + t;
            int row = s >> 2, c8 = s & 3;
            gld16(&Xb[(size_t)(m0 + row) * 1024 + k0 + c8 * 8], &Alds[s * 8]);
        }
#pragma unroll
        for (int it = 0; it < 2; ++it) {
            int s = it * 256 + t;
            int row = s >> 2, c8 = s & 3;
            gld16(&Wt[(size_t)(n0 + row) * 1024 + k0 + c8 * 8], &Blds[s * 8]);
        }
        __syncthreads();
        bf16x8 aF[4], bF[4];
#pragma unroll
        for (int mf = 0; mf < 4; ++mf)
            aF[mf] = *(const bf16x8*)&Alds[(wm * 64 + mf * 16 + lr) * 32 + lg4 * 8];
#pragma unroll
        for (int nf = 0; nf < 4; ++nf)
            bF[nf] = *(const bf16x8*)&Blds[(wn * 64 + nf * 16 + lr) * 32 + lg4 * 8];
#pragma unroll
        for (int mf = 0; mf < 4; ++mf)
#pragma unroll
            for (int nf = 0; nf < 4; ++nf)
                acc[mf][nf] = __builtin_amdgcn_mfma_f32_16x16x32_bf16(
                    aF[mf], bF[nf], acc[mf][nf], 0, 0, 0);
    }
#pragma unroll
    for (int mf = 0; mf < 4; ++mf) {
#pragma unroll
        for (int nf = 0; nf < 4; ++nf) {
            int col = n0 + wn * 64 + nf * 16 + lr;
            float bias = (col < 1024) ? bq[col] : bk[col - 1024];
            float scale = (col < 1024) ? 0.0625f : 1.0f;
            short* dst = (col < 1024) ? Qb : Kb;
            int h = (col >> 8) & 3, d = col & 255;
#pragma unroll
            for (int r = 0; r < 4; ++r) {
                int rowg = m0 + wm * 64 + mf * 16 + lg4 * 4 + r;
                int b_ = rowg >> 10, i_ = rowg & 1023;
                float v = (acc[mf][nf][r] + bias) * scale;
                dst[((size_t)(b_ * 4 + h) * 1024 + i_) * 256 + d] = f2bf(v);
            }
        }
    }
}

// ---- 5. pass 1: Z[bh,i] = sum_{valid j} exp(s) ------------------------------
// K j-tile staged d-chunk-major: LDS slot s(16B) <-> (kc=s>>4, jj=s&15)
__global__ LB void k_stats(const short* __restrict__ Qb, const short* __restrict__ Kb,
                           const int* __restrict__ vm, float* __restrict__ Zr) {
    __shared__ short Ks[16 * 256];                     // 8 KB
    const int t = threadIdx.x, lane = t & 63, wid = t >> 6;
    const int bh = blockIdx.x >> 4, tile = blockIdx.x & 15;
    const int b = bh >> 2;
    const int i0 = tile * 64 + wid * 16;
    const int lr = lane & 15, lg4 = lane >> 4;
    bf16x8 aF[8];
    const short* qrow = &Qb[((size_t)bh * 1024 + i0 + lr) * 256];
#pragma unroll
    for (int kk = 0; kk < 8; ++kk) aF[kk] = *(const bf16x8*)&qrow[kk * 32 + lg4 * 8];
    float Z[4] = {0.f, 0.f, 0.f, 0.f};
    for (int j0 = 0; j0 < 1024; j0 += 16) {
        __syncthreads();
#pragma unroll
        for (int it = 0; it < 2; ++it) {
            int s = it * 256 + t;
            int jj = s & 15, kc = s >> 4;
            gld16(&Kb[((size_t)bh * 1024 + j0 + jj) * 256 + kc * 8], &Ks[s * 8]);
        }
        __syncthreads();
        f32x4 acc = {0.f, 0.f, 0.f, 0.f};
#pragma unroll
        for (int kk = 0; kk < 8; ++kk) {
            int kc = kk * 4 + lg4;
            bf16x8 bF = *(const bf16x8*)&Ks[(kc * 16 + lr) * 8];
            acc = __builtin_amdgcn_mfma_f32_16x16x32_bf16(aF[kk], bF, acc, 0, 0, 0);
        }
        int j = j0 + lr;
        int okj = vm[b * 1024 + j];
#pragma unroll
        for (int r = 0; r < 4; ++r) {
            int ir = i0 + lg4 * 4 + r;
            float e = __expf(acc[r]);
            Z[r] += (okj && (j > ir)) ? e : 0.f;
        }
    }
#pragma unroll
    for (int off = 1; off < 16; off <<= 1) {
#pragma unroll
        for (int r = 0; r < 4; ++r) Z[r] += __shfl_xor(Z[r], off);
    }
    if (lr < 4) Zr[bh * 1024 + i0 + lg4 * 4 + lr] = Z[lr];
}

// ---- 6. c[bh,i] = lg - log(Z)  (Z==0 -> dead row, c unused) -----------------
__global__ LB void k_c(const float* __restrict__ lgA, const float* __restrict__ Zr,
                       float* __restrict__ cc) {
    int idx = blockIdx.x * 256 + threadIdx.x;          // 32768
    int bh = idx >> 10, i = idx & 1023;
    int b = bh >> 2, h = bh & 3;
    float Zv = Zr[idx];
    float lgv = lgA[(b * 1024 + i) * 4 + h];
    cc[idx] = lgv - (Zv > 0.f ? __logf(Zv) : 0.f);
}

// ---- 7. pass 2: out[b,i,j] --------------------------------------------------
__global__ LB void k_out(const short* __restrict__ Qb, const short* __restrict__ Kb,
                         const int* __restrict__ vm, const float* __restrict__ cc,
                         float* __restrict__ out) {
    __shared__ short Ks[4 * 16 * 256];                 // 32 KB, per-head d-chunk-major
    const int t = threadIdx.x, lane = t & 63, wid = t >> 6;
    const int b = blockIdx.x >> 5;
    const int rest = blockIdx.x & 31;
    const int tile = rest >> 1, jh = rest & 1;
    const int i0 = tile * 64 + wid * 16;
    const int lr = lane & 15, lg4 = lane >> 4;
    bf16x8 aF[4][8];
#pragma unroll
    for (int h = 0; h < 4; ++h) {
        const short* qrow = &Qb[((size_t)(b * 4 + h) * 1024 + i0 + lr) * 256];
#pragma unroll
        for (int kk = 0; kk < 8; ++kk) aF[h][kk] = *(const bf16x8*)&qrow[kk * 32 + lg4 * 8];
    }
    float cr[4][4];
#pragma unroll
    for (int r = 0; r < 4; ++r)
#pragma unroll
        for (int h = 0; h < 4; ++h)
            cr[r][h] = cc[(b * 4 + h) * 1024 + i0 + lg4 * 4 + r];
    for (int j0 = jh * 512; j0 < jh * 512 + 512; j0 += 16) {
        __syncthreads();
#pragma unroll
        for (int it = 0; it < 8; ++it) {
            int s = it * 256 + t;
            int h = s >> 9, s2 = s & 511;
            int jj = s2 & 15, kc = s2 >> 4;
            gld16(&Kb[((size_t)(b * 4 + h) * 1024 + j0 + jj) * 256 + kc * 8], &Ks[s * 8]);
        }
        __syncthreads();
        f32x4 acc[4] = {};
#pragma unroll
        for (int h = 0; h < 4; ++h)
#pragma unroll
            for (int kk = 0; kk < 8; ++kk) {
                int kc = kk * 4 + lg4;
                bf16x8 bF = *(const bf16x8*)&Ks[h * 4096 + (kc * 16 + lr) * 8];
                acc[h] = __builtin_amdgcn_mfma_f32_16x16x32_bf16(aF[h][kk], bF, acc[h], 0, 0, 0);
            }
        int j = j0 + lr;
        int okj = vm[b * 1024 + j];
#pragma unroll
        for (int r = 0; r < 4; ++r) {
            int ir = i0 + lg4 * 4 + r;
            float o;
            if (okj && (j > ir)) {
                float s0 = __expf(acc[0][r] + cr[r][0]) + __expf(acc[1][r] + cr[r][1])
                         + __expf(acc[2][r] + cr[r][2]) + __expf(acc[3][r] + cr[r][3]);
                o = __logf(s0);
            } else {
                o = -1.0e9f;
            }
            out[((size_t)(b * 1024 + ir)) * 1024 + j] = o;
        }
    }
}

// ---------------------------------------------------------------------------
extern "C" void kernel_launch(void* const* d_in, const int* in_sizes, int n_in,
                              void* d_out, int out_size, void* d_ws, size_t ws_size,
                              hipStream_t stream) {
    const float* features = (const float*)d_in[0];
    const int*   vmask    = (const int*)d_in[1];
    const float* Wq       = (const float*)d_in[2];
    const float* bq       = (const float*)d_in[3];
    const float* Wk       = (const float*)d_in[4];
    const float* bk       = (const float*)d_in[5];
    const float* Wg       = (const float*)d_in[6];
    const float* bg       = (const float*)d_in[7];
    float* out = (float*)d_out;

    // ws carve (~55 MB)
    short* Xb = (short*)d_ws;                  // [8192][1024] bf16
    short* Wt = Xb + 8388608;                  // [2048][1024] bf16 (W^T, q then k)
    short* Qb = Wt + 2097152;                  // [32 bh][1024 i][256 d] bf16 (pre-scaled 1/16)
    short* Kb = Qb + 8388608;                  // [32 bh][1024 j][256 d] bf16
    float* lgA = (float*)(Kb + 8388608);       // [8192][4]
    float* Zr  = lgA + 32768;                  // [32 bh][1024 i]
    float* cc  = Zr + 32768;                   // [32 bh][1024 i]

    k_cvt_x<<<4096, 256, 0, stream>>>(features, Xb);
    k_cvt_w<<<dim3(64, 32), dim3(32, 8), 0, stream>>>(Wq, Wk, Wt);
    k_gates<<<2048, 256, 0, stream>>>(features, Wg, bg, lgA);
    k_gemm<<<1024, 256, 0, stream>>>(Xb, Wt, bq, bk, Qb, Kb);
    k_stats<<<512, 256, 0, stream>>>(Qb, Kb, vmask, Zr);
    k_c<<<128, 256, 0, stream>>>(lgA, Zr, cc);
    k_out<<<256, 256, 0, stream>>>(Qb, Kb, vmask, cc, out);
}

// Round 2
// 180.326 us; speedup vs baseline: 1.1635x; 1.1635x over previous
//
#include <hip/hip_runtime.h>

// ---------------------------------------------------------------------------
// DagLinkExtractor: B=8, N=1024, HID=1024, NH=4, HD=256
// out[b,i,j] = logsumexp_h( s_masked[b,i,j,h] + c[b,i,h] )
//   s = (Q_h . K_h)/16  (1/16 folded into stored Q)
//   c[b,i,h] = log_gate[b,i,h] - log(sum_{valid j>i} exp(s))
//   masked / dead-row positions -> exactly -1e9f
// ---------------------------------------------------------------------------

typedef __attribute__((ext_vector_type(8))) short bf16x8;
typedef __attribute__((ext_vector_type(4))) float f32x4;

#define LB __launch_bounds__(256)

__device__ __forceinline__ short f2bf(float f) {
    unsigned u = __float_as_uint(f);
    u += 0x7fffu + ((u >> 16) & 1u);   // RNE
    return (short)(u >> 16);
}

__device__ __forceinline__ void gld16(const void* g, void* l) {
    __builtin_amdgcn_global_load_lds(
        (const __attribute__((address_space(1))) unsigned int*)g,
        (__attribute__((address_space(3))) unsigned int*)l, 16, 0, 0);
}

// ---- 1. features f32 -> bf16 ------------------------------------------------
__global__ LB void k_cvt_x(const float* __restrict__ src, short* __restrict__ dst) {
    int idx = blockIdx.x * 256 + threadIdx.x;
    const float4* s4 = (const float4*)src;
    float4 a = s4[idx * 2], b = s4[idx * 2 + 1];
    bf16x8 o;
    o[0] = f2bf(a.x); o[1] = f2bf(a.y); o[2] = f2bf(a.z); o[3] = f2bf(a.w);
    o[4] = f2bf(b.x); o[5] = f2bf(b.y); o[6] = f2bf(b.z); o[7] = f2bf(b.w);
    *(bf16x8*)&dst[idx * 8] = o;
}

// ---- 2. Wt[n][k] = W[k][n] (bf16), n<1024 -> Wq, else Wk --------------------
__global__ LB void k_cvt_w(const float* __restrict__ Wq, const float* __restrict__ Wk,
                           short* __restrict__ Wt) {
    __shared__ float tile[32][33];
    int n0 = blockIdx.x * 32, k0 = blockIdx.y * 32;
    const float* W = (n0 < 1024) ? Wq : Wk;
    int nb = n0 & 1023;
    int tx = threadIdx.x, ty = threadIdx.y;
#pragma unroll
    for (int jj = 0; jj < 4; ++jj) {
        int k = ty + jj * 8;
        tile[k][tx] = W[(size_t)(k0 + k) * 1024 + nb + tx];
    }
    __syncthreads();
#pragma unroll
    for (int jj = 0; jj < 4; ++jj) {
        int n = ty + jj * 8;
        Wt[(size_t)(n0 + n) * 1024 + k0 + tx] = f2bf(tile[tx][n]);
    }
}

// ---- 3. log_gates[b,i,h] ----------------------------------------------------
__global__ LB void k_gates(const float* __restrict__ feat, const float* __restrict__ Wg,
                           const float* __restrict__ bg, float* __restrict__ lgA) {
    int row = blockIdx.x * 4 + (threadIdx.x >> 6);
    int lane = threadIdx.x & 63;
    const float* f = feat + (size_t)row * 1024;
    float g0 = 0.f, g1 = 0.f, g2 = 0.f, g3 = 0.f;
#pragma unroll
    for (int t = 0; t < 16; ++t) {
        int k = lane + t * 64;
        float x = f[k];
        float4 w = *(const float4*)&Wg[k * 4];
        g0 += x * w.x; g1 += x * w.y; g2 += x * w.z; g3 += x * w.w;
    }
#pragma unroll
    for (int off = 32; off; off >>= 1) {
        g0 += __shfl_xor(g0, off); g1 += __shfl_xor(g1, off);
        g2 += __shfl_xor(g2, off); g3 += __shfl_xor(g3, off);
    }
    g0 += bg[0]; g1 += bg[1]; g2 += bg[2]; g3 += bg[3];
    float m = fmaxf(fmaxf(g0, g1), fmaxf(g2, g3));
    float s = __expf(g0 - m) + __expf(g1 - m) + __expf(g2 - m) + __expf(g3 - m);
    float ls = m + __logf(s);
    if (lane == 0) {
        float4 o = {g0 - ls, g1 - ls, g2 - ls, g3 - ls};
        *(float4*)&lgA[row * 4] = o;
    }
}

// ---- 4. GEMM: Q = X@Wq+bq (scaled 1/16), K = X@Wk+bk; bf16 out, head layout -
__global__ LB void k_gemm(const short* __restrict__ Xb, const short* __restrict__ Wt,
                          const float* __restrict__ bq, const float* __restrict__ bk,
                          short* __restrict__ Qb, short* __restrict__ Kb) {
    __shared__ short Alds[128 * 32];
    __shared__ short Blds[128 * 32];
    const int t = threadIdx.x;
    const int lane = t & 63, wid = t >> 6;
    const int wm = wid >> 1, wn = wid & 1;
    const int m0 = (blockIdx.x >> 4) * 128, n0 = (blockIdx.x & 15) * 128;
    const int lr = lane & 15, lg4 = lane >> 4;
    f32x4 acc[4][4] = {};
    for (int k0 = 0; k0 < 1024; k0 += 32) {
        __syncthreads();
#pragma unroll
        for (int it = 0; it < 2; ++it) {
            int s = it * 256 + t;
            int row = s >> 2, c8 = s & 3;
            gld16(&Xb[(size_t)(m0 + row) * 1024 + k0 + c8 * 8], &Alds[s * 8]);
        }
#pragma unroll
        for (int it = 0; it < 2; ++it) {
            int s = it * 256 + t;
            int row = s >> 2, c8 = s & 3;
            gld16(&Wt[(size_t)(n0 + row) * 1024 + k0 + c8 * 8], &Blds[s * 8]);
        }
        __syncthreads();
        bf16x8 aF[4], bF[4];
#pragma unroll
        for (int mf = 0; mf < 4; ++mf)
            aF[mf] = *(const bf16x8*)&Alds[(wm * 64 + mf * 16 + lr) * 32 + lg4 * 8];
#pragma unroll
        for (int nf = 0; nf < 4; ++nf)
            bF[nf] = *(const bf16x8*)&Blds[(wn * 64 + nf * 16 + lr) * 32 + lg4 * 8];
#pragma unroll
        for (int mf = 0; mf < 4; ++mf)
#pragma unroll
            for (int nf = 0; nf < 4; ++nf)
                acc[mf][nf] = __builtin_amdgcn_mfma_f32_16x16x32_bf16(
                    aF[mf], bF[nf], acc[mf][nf], 0, 0, 0);
    }
#pragma unroll
    for (int mf = 0; mf < 4; ++mf) {
#pragma unroll
        for (int nf = 0; nf < 4; ++nf) {
            int col = n0 + wn * 64 + nf * 16 + lr;
            float bias = (col < 1024) ? bq[col] : bk[col - 1024];
            float scale = (col < 1024) ? 0.0625f : 1.0f;
            short* dst = (col < 1024) ? Qb : Kb;
            int h = (col >> 8) & 3, d = col & 255;
#pragma unroll
            for (int r = 0; r < 4; ++r) {
                int rowg = m0 + wm * 64 + mf * 16 + lg4 * 4 + r;
                int b_ = rowg >> 10, i_ = rowg & 1023;
                float v = (acc[mf][nf][r] + bias) * scale;
                dst[((size_t)(b_ * 4 + h) * 1024 + i_) * 256 + d] = f2bf(v);
            }
        }
    }
}

// ---- 5. pass 1: partial Z[jt][bh,i] = sum_{valid j>i, j in jt} exp(s) -------
// grid: bh(32) x it(16) x jt(4) = 2048 blocks, 256 thr
__global__ LB void k_stats(const short* __restrict__ Qb, const short* __restrict__ Kb,
                           const int* __restrict__ vm, float* __restrict__ Zp) {
    __shared__ short Ks[16 * 256];                     // 8 KB d-chunk-major
    const int t = threadIdx.x, lane = t & 63, wid = t >> 6;
    const int jt = blockIdx.x & 3;
    const int it = (blockIdx.x >> 2) & 15;
    const int bh = blockIdx.x >> 6;
    const int b = bh >> 2;
    const int i0blk = it * 64;
    const int i0 = i0blk + wid * 16;
    const int lr = lane & 15, lg4 = lane >> 4;
    const int jlo = jt * 256, jhi = jlo + 256;
    const int jstart = (jlo > i0blk) ? jlo : i0blk;    // causal: first useful 16-step
    float Z[4] = {0.f, 0.f, 0.f, 0.f};
    if (jstart < jhi) {
        bf16x8 aF[8];
        const short* qrow = &Qb[((size_t)bh * 1024 + i0 + lr) * 256];
#pragma unroll
        for (int kk = 0; kk < 8; ++kk) aF[kk] = *(const bf16x8*)&qrow[kk * 32 + lg4 * 8];
        for (int j0 = jstart; j0 < jhi; j0 += 16) {
            __syncthreads();
#pragma unroll
            for (int itr = 0; itr < 2; ++itr) {
                int s = itr * 256 + t;
                int jj = s & 15, kc = s >> 4;
                gld16(&Kb[((size_t)bh * 1024 + j0 + jj) * 256 + kc * 8], &Ks[s * 8]);
            }
            __syncthreads();
            if (j0 + 15 <= i0) continue;               // this wave fully masked
            f32x4 acc = {0.f, 0.f, 0.f, 0.f};
#pragma unroll
            for (int kk = 0; kk < 8; ++kk) {
                int kc = kk * 4 + lg4;
                bf16x8 bF = *(const bf16x8*)&Ks[(kc * 16 + lr) * 8];
                acc = __builtin_amdgcn_mfma_f32_16x16x32_bf16(aF[kk], bF, acc, 0, 0, 0);
            }
            int j = j0 + lr;
            int okj = vm[b * 1024 + j];
#pragma unroll
            for (int r = 0; r < 4; ++r) {
                int ir = i0 + lg4 * 4 + r;
                float e = __expf(acc[r]);
                Z[r] += (okj && (j > ir)) ? e : 0.f;
            }
        }
    }
#pragma unroll
    for (int off = 1; off < 16; off <<= 1) {
#pragma unroll
        for (int r = 0; r < 4; ++r) Z[r] += __shfl_xor(Z[r], off);
    }
    if (lr < 4) Zp[jt * 32768 + bh * 1024 + i0 + lg4 * 4 + lr] = Z[lr];
}

// ---- 6. c[bh,i] = lg - log(sum_jt Zp) ---------------------------------------
__global__ LB void k_c(const float* __restrict__ lgA, const float* __restrict__ Zp,
                       float* __restrict__ cc) {
    int idx = blockIdx.x * 256 + threadIdx.x;          // 32768
    int bh = idx >> 10, i = idx & 1023;
    int b = bh >> 2, h = bh & 3;
    float Zv = Zp[idx] + Zp[32768 + idx] + Zp[65536 + idx] + Zp[98304 + idx];
    float lgv = lgA[(b * 1024 + i) * 4 + h];
    cc[idx] = lgv - (Zv > 0.f ? __logf(Zv) : 0.f);
}

// ---- 7. pass 2: out[b,i,j] --------------------------------------------------
// grid: b(8) x it(16) x jt(8) = 1024 blocks, 512 thr (8 waves = 4 heads x 2 i-halves)
__global__ __launch_bounds__(512) void k_out(const short* __restrict__ Qb,
                                             const short* __restrict__ Kb,
                                             const int* __restrict__ vm,
                                             const float* __restrict__ cc,
                                             float* __restrict__ out) {
    __shared__ short Ks[4 * 16 * 256];                 // 32 KB per-head d-chunk-major
    __shared__ float P[4][16][68];                     // 17.4 KB, pad 68 -> conflict-free
    const int t = threadIdx.x, lane = t & 63, wid = t >> 6;
    const int wh = wid >> 1, wi = wid & 1;
    const int jt = blockIdx.x & 7;
    const int it = (blockIdx.x >> 3) & 15;
    const int b = blockIdx.x >> 7;
    const int i0blk = it * 64, jlo = jt * 128;
    const int lr = lane & 15, lg4 = lane >> 4;

    if (jlo + 127 <= i0blk) {                          // whole tile strictly lower-tri
        float4 m4 = {-1.0e9f, -1.0e9f, -1.0e9f, -1.0e9f};
        int r = t >> 3, cg = t & 7;                    // 64 rows x 8 groups x 16 floats
        float4* p4 = (float4*)&out[((size_t)(b * 1024) + i0blk + r) * 1024 + jlo + cg * 16];
        p4[0] = m4; p4[1] = m4; p4[2] = m4; p4[3] = m4;
        return;
    }

    // Q fragments: head wh, rows i0blk + wi*32 + f*16 + lr
    bf16x8 aF[2][8];
    float cr[2][4];
#pragma unroll
    for (int f = 0; f < 2; ++f) {
        const short* qrow = &Qb[((size_t)(b * 4 + wh) * 1024 + i0blk + wi * 32 + f * 16 + lr) * 256];
#pragma unroll
        for (int kk = 0; kk < 8; ++kk) aF[f][kk] = *(const bf16x8*)&qrow[kk * 32 + lg4 * 8];
#pragma unroll
        for (int r = 0; r < 4; ++r)
            cr[f][r] = cc[(b * 4 + wh) * 1024 + i0blk + wi * 32 + f * 16 + lg4 * 4 + r];
    }
    const int i0w = i0blk + wi * 32;

    for (int j0 = jlo; j0 < jlo + 128; j0 += 16) {
        __syncthreads();
#pragma unroll
        for (int itr = 0; itr < 4; ++itr) {            // 32 KB: 2048 x 16B / 512 thr
            int s = itr * 512 + t;
            int h = s >> 9, s2 = s & 511, jj = s2 & 15, kc = s2 >> 4;
            gld16(&Kb[((size_t)(b * 4 + h) * 1024 + j0 + jj) * 256 + kc * 8], &Ks[s * 8]);
        }
        __syncthreads();
#pragma unroll
        for (int f = 0; f < 2; ++f) {
            if (j0 + 15 <= i0w + f * 16) continue;     // wave-uniform causal skip
            f32x4 acc = {0.f, 0.f, 0.f, 0.f};
#pragma unroll
            for (int kk = 0; kk < 8; ++kk) {
                int kc = kk * 4 + lg4;
                bf16x8 bF = *(const bf16x8*)&Ks[(wh * 512 + kc * 16 + lr) * 8];
                acc = __builtin_amdgcn_mfma_f32_16x16x32_bf16(aF[f][kk], bF, acc, 0, 0, 0);
            }
            float4 e4;
            e4.x = __expf(acc[0] + cr[f][0]);
            e4.y = __expf(acc[1] + cr[f][1]);
            e4.z = __expf(acc[2] + cr[f][2]);
            e4.w = __expf(acc[3] + cr[f][3]);
            *(float4*)&P[wh][lr][wi * 32 + f * 16 + lg4 * 4] = e4;
        }
        __syncthreads();
        // combine: 64 i x 16 j outputs, 2 per thread
#pragma unroll
        for (int e2 = 0; e2 < 2; ++e2) {
            int el = e2 * 512 + t;
            int j = el & 15, i = el >> 4;
            int gi = i0blk + i, gj = j0 + j;
            float o = -1.0e9f;
            if ((gj > gi) && vm[b * 1024 + gj]) {
                float s0 = P[0][j][i] + P[1][j][i] + P[2][j][i] + P[3][j][i];
                o = __logf(s0);
            }
            out[((size_t)(b * 1024) + gi) * 1024 + gj] = o;
        }
    }
}

// ---------------------------------------------------------------------------
extern "C" void kernel_launch(void* const* d_in, const int* in_sizes, int n_in,
                              void* d_out, int out_size, void* d_ws, size_t ws_size,
                              hipStream_t stream) {
    const float* features = (const float*)d_in[0];
    const int*   vmask    = (const int*)d_in[1];
    const float* Wq       = (const float*)d_in[2];
    const float* bq       = (const float*)d_in[3];
    const float* Wk       = (const float*)d_in[4];
    const float* bk       = (const float*)d_in[5];
    const float* Wg       = (const float*)d_in[6];
    const float* bg       = (const float*)d_in[7];
    float* out = (float*)d_out;

    // ws carve (~53 MB)
    short* Xb = (short*)d_ws;                  // [8192][1024] bf16
    short* Wt = Xb + 8388608;                  // [2048][1024] bf16 (W^T, q then k)
    short* Qb = Wt + 2097152;                  // [32 bh][1024 i][256 d] bf16 (pre-scaled 1/16)
    short* Kb = Qb + 8388608;                  // [32 bh][1024 j][256 d] bf16
    float* lgA = (float*)(Kb + 8388608);       // [8192][4]
    float* Zp  = lgA + 32768;                  // [4 jt][32 bh][1024 i]
    float* cc  = Zp + 131072;                  // [32 bh][1024 i]

    k_cvt_x<<<4096, 256, 0, stream>>>(features, Xb);
    k_cvt_w<<<dim3(64, 32), dim3(32, 8), 0, stream>>>(Wq, Wk, Wt);
    k_gates<<<2048, 256, 0, stream>>>(features, Wg, bg, lgA);
    k_gemm<<<1024, 256, 0, stream>>>(Xb, Wt, bq, bk, Qb, Kb);
    k_stats<<<2048, 256, 0, stream>>>(Qb, Kb, vmask, Zp);
    k_c<<<128, 256, 0, stream>>>(lgA, Zp, cc);
    k_out<<<1024, 512, 0, stream>>>(Qb, Kb, vmask, cc, out);
}

// Round 3
// 165.441 us; speedup vs baseline: 1.2682x; 1.0900x over previous
//
#include <hip/hip_runtime.h>

// ---------------------------------------------------------------------------
// DagLinkExtractor: B=8, N=1024, HID=1024, NH=4, HD=256
// out[b,i,j] = logsumexp_h( s_masked[b,i,j,h] + c[b,i,h] )
//   s = (Q_h . K_h)/16  (1/16 folded into stored Q)
//   c[b,i,h] = log_gate[b,i,h] - log(sum_{valid j>i} exp(s))
//   masked / dead-row positions -> exactly -1e9f
// ---------------------------------------------------------------------------

typedef __attribute__((ext_vector_type(8))) short bf16x8;
typedef __attribute__((ext_vector_type(4))) short bf16x4;
typedef __attribute__((ext_vector_type(4))) float f32x4;

#define LB __launch_bounds__(256)

__device__ __forceinline__ short f2bf(float f) {
    unsigned u = __float_as_uint(f);
    u += 0x7fffu + ((u >> 16) & 1u);   // RNE
    return (short)(u >> 16);
}
__device__ __forceinline__ float bf2f(short s) {
    return __uint_as_float(((unsigned)(unsigned short)s) << 16);
}

__device__ __forceinline__ void gld16(const void* g, void* l) {
    __builtin_amdgcn_global_load_lds(
        (const __attribute__((address_space(1))) unsigned int*)g,
        (__attribute__((address_space(3))) unsigned int*)l, 16, 0, 0);
}

// ---- 1. features f32 -> bf16 ------------------------------------------------
__global__ LB void k_cvt_x(const float* __restrict__ src, short* __restrict__ dst) {
    int idx = blockIdx.x * 256 + threadIdx.x;
    const float4* s4 = (const float4*)src;
    float4 a = s4[idx * 2], b = s4[idx * 2 + 1];
    bf16x8 o;
    o[0] = f2bf(a.x); o[1] = f2bf(a.y); o[2] = f2bf(a.z); o[3] = f2bf(a.w);
    o[4] = f2bf(b.x); o[5] = f2bf(b.y); o[6] = f2bf(b.z); o[7] = f2bf(b.w);
    *(bf16x8*)&dst[idx * 8] = o;
}

// ---- 2. Wt[n][k] = W[k][n] (bf16), n<1024 -> Wq, else Wk --------------------
__global__ LB void k_cvt_w(const float* __restrict__ Wq, const float* __restrict__ Wk,
                           short* __restrict__ Wt) {
    __shared__ float tile[32][33];
    int n0 = blockIdx.x * 32, k0 = blockIdx.y * 32;
    const float* W = (n0 < 1024) ? Wq : Wk;
    int nb = n0 & 1023;
    int tx = threadIdx.x, ty = threadIdx.y;
#pragma unroll
    for (int jj = 0; jj < 4; ++jj) {
        int k = ty + jj * 8;
        tile[k][tx] = W[(size_t)(k0 + k) * 1024 + nb + tx];
    }
    __syncthreads();
#pragma unroll
    for (int jj = 0; jj < 4; ++jj) {
        int n = ty + jj * 8;
        Wt[(size_t)(n0 + n) * 1024 + k0 + tx] = f2bf(tile[tx][n]);
    }
}

// ---- 3. log_gates[b,i,h] ----------------------------------------------------
__global__ LB void k_gates(const float* __restrict__ feat, const float* __restrict__ Wg,
                           const float* __restrict__ bg, float* __restrict__ lgA) {
    int row = blockIdx.x * 4 + (threadIdx.x >> 6);
    int lane = threadIdx.x & 63;
    const float* f = feat + (size_t)row * 1024;
    float g0 = 0.f, g1 = 0.f, g2 = 0.f, g3 = 0.f;
#pragma unroll
    for (int t = 0; t < 16; ++t) {
        int k = lane + t * 64;
        float x = f[k];
        float4 w = *(const float4*)&Wg[k * 4];
        g0 += x * w.x; g1 += x * w.y; g2 += x * w.z; g3 += x * w.w;
    }
#pragma unroll
    for (int off = 32; off; off >>= 1) {
        g0 += __shfl_xor(g0, off); g1 += __shfl_xor(g1, off);
        g2 += __shfl_xor(g2, off); g3 += __shfl_xor(g3, off);
    }
    g0 += bg[0]; g1 += bg[1]; g2 += bg[2]; g3 += bg[3];
    float m = fmaxf(fmaxf(g0, g1), fmaxf(g2, g3));
    float s = __expf(g0 - m) + __expf(g1 - m) + __expf(g2 - m) + __expf(g3 - m);
    float ls = m + __logf(s);
    if (lane == 0) {
        float4 o = {g0 - ls, g1 - ls, g2 - ls, g3 - ls};
        *(float4*)&lgA[row * 4] = o;
    }
}

// ---- 4. GEMM: Q = X@Wq+bq (scaled 1/16), K = X@Wk+bk; bf16 out, head layout -
__global__ LB void k_gemm(const short* __restrict__ Xb, const short* __restrict__ Wt,
                          const float* __restrict__ bq, const float* __restrict__ bk,
                          short* __restrict__ Qb, short* __restrict__ Kb) {
    __shared__ short Alds[128 * 32];
    __shared__ short Blds[128 * 32];
    const int t = threadIdx.x;
    const int lane = t & 63, wid = t >> 6;
    const int wm = wid >> 1, wn = wid & 1;
    const int m0 = (blockIdx.x >> 4) * 128, n0 = (blockIdx.x & 15) * 128;
    const int lr = lane & 15, lg4 = lane >> 4;
    f32x4 acc[4][4] = {};
    for (int k0 = 0; k0 < 1024; k0 += 32) {
        __syncthreads();
#pragma unroll
        for (int it = 0; it < 2; ++it) {
            int s = it * 256 + t;
            int row = s >> 2, c8 = s & 3;
            gld16(&Xb[(size_t)(m0 + row) * 1024 + k0 + c8 * 8], &Alds[s * 8]);
        }
#pragma unroll
        for (int it = 0; it < 2; ++it) {
            int s = it * 256 + t;
            int row = s >> 2, c8 = s & 3;
            gld16(&Wt[(size_t)(n0 + row) * 1024 + k0 + c8 * 8], &Blds[s * 8]);
        }
        __syncthreads();
        bf16x8 aF[4], bF[4];
#pragma unroll
        for (int mf = 0; mf < 4; ++mf)
            aF[mf] = *(const bf16x8*)&Alds[(wm * 64 + mf * 16 + lr) * 32 + lg4 * 8];
#pragma unroll
        for (int nf = 0; nf < 4; ++nf)
            bF[nf] = *(const bf16x8*)&Blds[(wn * 64 + nf * 16 + lr) * 32 + lg4 * 8];
#pragma unroll
        for (int mf = 0; mf < 4; ++mf)
#pragma unroll
            for (int nf = 0; nf < 4; ++nf)
                acc[mf][nf] = __builtin_amdgcn_mfma_f32_16x16x32_bf16(
                    aF[mf], bF[nf], acc[mf][nf], 0, 0, 0);
    }
#pragma unroll
    for (int mf = 0; mf < 4; ++mf) {
#pragma unroll
        for (int nf = 0; nf < 4; ++nf) {
            int col = n0 + wn * 64 + nf * 16 + lr;
            float bias = (col < 1024) ? bq[col] : bk[col - 1024];
            float scale = (col < 1024) ? 0.0625f : 1.0f;
            short* dst = (col < 1024) ? Qb : Kb;
            int h = (col >> 8) & 3, d = col & 255;
#pragma unroll
            for (int r = 0; r < 4; ++r) {
                int rowg = m0 + wm * 64 + mf * 16 + lg4 * 4 + r;
                int b_ = rowg >> 10, i_ = rowg & 1023;
                float v = (acc[mf][nf][r] + bias) * scale;
                dst[((size_t)(b_ * 4 + h) * 1024 + i_) * 256 + d] = f2bf(v);
            }
        }
    }
}

// ---- 5. pass 1: partial Z[jt][bh,i] = sum_{valid j>i, j in jt} exp(s) -------
// grid 2048 (XCD-chunked), 256 thr; double-buffered K staging
__global__ __launch_bounds__(256, 4) void k_stats(const short* __restrict__ Qb,
                                                  const short* __restrict__ Kb,
                                                  const int* __restrict__ vm,
                                                  float* __restrict__ Zp) {
    __shared__ short Ks[2][4096];                      // 2 x 8 KB, d-chunk-major
    const int t = threadIdx.x, lane = t & 63, wid = t >> 6;
    const int wgid = ((blockIdx.x & 7) << 8) | (blockIdx.x >> 3);  // XCD-chunked
    const int jt = wgid & 3;
    const int it = (wgid >> 2) & 15;
    const int bh = wgid >> 6;
    const int b = bh >> 2;
    const int i0blk = it * 64;
    const int i0 = i0blk + wid * 16;
    const int lr = lane & 15, lg4 = lane >> 4;
    const int jlo = jt * 256, jhi = jlo + 256;
    const int jstart = (jlo > i0blk) ? jlo : i0blk;
    float Z[4] = {0.f, 0.f, 0.f, 0.f};
    if (jstart < jhi) {
        bf16x8 aF[8];
        const short* qrow = &Qb[((size_t)bh * 1024 + i0 + lr) * 256];
#pragma unroll
        for (int kk = 0; kk < 8; ++kk) aF[kk] = *(const bf16x8*)&qrow[kk * 32 + lg4 * 8];
#pragma unroll
        for (int kk = 0; kk < 8; ++kk) asm volatile("" : "+v"(aF[kk]));
        unsigned vmbits = 0;
#pragma unroll
        for (int st = 0; st < 16; ++st)
            vmbits |= (vm[b * 1024 + jlo + st * 16 + lr] ? 1u : 0u) << st;
#pragma unroll
        for (int itr = 0; itr < 2; ++itr) {            // prologue stage -> buf 0
            int s = itr * 256 + t, jj = s & 15, kc = s >> 4;
            gld16(&Kb[((size_t)bh * 1024 + jstart + jj) * 256 + kc * 8], &Ks[0][s * 8]);
        }
        asm volatile("s_waitcnt vmcnt(0)" ::: "memory");
        __builtin_amdgcn_sched_barrier(0);
        __builtin_amdgcn_s_barrier();
        const int nst = (jhi - jstart) >> 4;
        for (int stp = 0; stp < nst; ++stp) {
            const int j0 = jstart + stp * 16;
            const int cur = stp & 1;
            if (stp + 1 < nst) {
#pragma unroll
                for (int itr = 0; itr < 2; ++itr) {
                    int s = itr * 256 + t, jj = s & 15, kc = s >> 4;
                    gld16(&Kb[((size_t)bh * 1024 + j0 + 16 + jj) * 256 + kc * 8],
                          &Ks[cur ^ 1][s * 8]);
                }
            }
            if (j0 + 15 > i0) {                        // per-wave skip (no barrier inside)
                f32x4 acc = {0.f, 0.f, 0.f, 0.f};
#pragma unroll
                for (int kk = 0; kk < 8; ++kk) {
                    bf16x8 bF = *(const bf16x8*)&Ks[cur][((kk * 4 + lg4) * 16 + lr) * 8];
                    acc = __builtin_amdgcn_mfma_f32_16x16x32_bf16(aF[kk], bF, acc, 0, 0, 0);
                }
                const int okj = (vmbits >> ((j0 - jlo) >> 4)) & 1;
                const int j = j0 + lr;
#pragma unroll
                for (int r = 0; r < 4; ++r) {
                    int ir = i0 + lg4 * 4 + r;
                    Z[r] += (okj && (j > ir)) ? __expf(acc[r]) : 0.f;
                }
            }
            asm volatile("s_waitcnt vmcnt(0)" ::: "memory");
            __builtin_amdgcn_sched_barrier(0);
            __builtin_amdgcn_s_barrier();
        }
    }
#pragma unroll
    for (int off = 1; off < 16; off <<= 1) {
#pragma unroll
        for (int r = 0; r < 4; ++r) Z[r] += __shfl_xor(Z[r], off);
    }
    if (lr < 4) Zp[jt * 32768 + bh * 1024 + i0 + lg4 * 4 + lr] = Z[lr];
}

// ---- 6. c[bh,i] = lg - log(sum_jt Zp) ---------------------------------------
__global__ LB void k_c(const float* __restrict__ lgA, const float* __restrict__ Zp,
                       float* __restrict__ cc) {
    int idx = blockIdx.x * 256 + threadIdx.x;          // 32768
    int bh = idx >> 10, i = idx & 1023;
    int b = bh >> 2, h = bh & 3;
    float Zv = Zp[idx] + Zp[32768 + idx] + Zp[65536 + idx] + Zp[98304 + idx];
    float lgv = lgA[(b * 1024 + i) * 4 + h];
    cc[idx] = lgv - (Zv > 0.f ? __logf(Zv) : 0.f);
}

// ---- 7. pass 2: out[b,i,j] --------------------------------------------------
// grid 1024 (XCD-chunked: each XCD owns one b), 512 thr = 4 heads x 2 i-halves
__global__ __launch_bounds__(512, 4) void k_out(const short* __restrict__ Qb,
                                                const short* __restrict__ Kb,
                                                const int* __restrict__ vm,
                                                const float* __restrict__ cc,
                                                float* __restrict__ out) {
    __shared__ short Ks[2][16384];                     // 2 x 32 KB, per-head d-chunk-major
    __shared__ __align__(16) short Pb[16 * 260];       // [j][i][4h] bf16 + pad, 8.1 KB
    const int t = threadIdx.x, lane = t & 63, wid = t >> 6;
    const int wh = wid & 3, wi = wid >> 2;
    const int wgid = ((blockIdx.x & 7) << 7) | (blockIdx.x >> 3);  // XCD-chunked
    const int it = wgid & 15;
    const int jt = (wgid >> 4) & 7;
    const int b = wgid >> 7;
    const int i0blk = it * 64, jlo = jt * 128;
    const int b4 = b * 4;

    int jbeg = (i0blk > jlo) ? i0blk : jlo;            // fully-masked prefix -> fill
    if (jbeg > jlo + 128) jbeg = jlo + 128;
    {
        const float4 m4 = {-1.0e9f, -1.0e9f, -1.0e9f, -1.0e9f};
        const int r = t >> 3, cg = t & 7;
        for (int c0 = jlo; c0 < jbeg; c0 += 64) {
            float* p = &out[((size_t)(b * 1024) + i0blk + r) * 1024 + c0 + cg * 8];
            *(float4*)p = m4;
            *(float4*)(p + 4) = m4;
        }
    }
    if (jbeg == jlo + 128) return;                     // block-uniform, pre-barrier
    const int nst = (jlo + 128 - jbeg) >> 4;

    const int lr = lane & 15, lg4 = lane >> 4;
    const int i0w = i0blk + wi * 32;
    bf16x8 aF[2][8];
    float cr[2][4];
#pragma unroll
    for (int f = 0; f < 2; ++f) {
        const short* qrow = &Qb[((size_t)(b4 + wh) * 1024 + i0w + f * 16 + lr) * 256];
#pragma unroll
        for (int kk = 0; kk < 8; ++kk) aF[f][kk] = *(const bf16x8*)&qrow[kk * 32 + lg4 * 8];
#pragma unroll
        for (int r = 0; r < 4; ++r)
            cr[f][r] = cc[(b4 + wh) * 1024 + i0w + f * 16 + lg4 * 4 + r];
    }
#pragma unroll
    for (int kk = 0; kk < 8; ++kk)
        asm volatile("" : "+v"(aF[0][kk]), "+v"(aF[1][kk]));   // pin: no remat

    const int jL = t & 15, iL = t >> 4;
    unsigned vmbits = 0;
#pragma unroll
    for (int st = 0; st < 8; ++st)
        vmbits |= (vm[b * 1024 + jlo + st * 16 + jL] ? 1u : 0u) << st;

#pragma unroll
    for (int itr = 0; itr < 4; ++itr) {                // prologue stage -> buf 0
        int s = itr * 512 + t;
        int h = s >> 9, s2 = s & 511, jj = s2 & 15, kc = s2 >> 4;
        gld16(&Kb[((size_t)(b4 + h) * 1024 + jbeg + jj) * 256 + kc * 8], &Ks[0][s * 8]);
    }
    asm volatile("s_waitcnt vmcnt(0)" ::: "memory");
    __builtin_amdgcn_sched_barrier(0);
    __builtin_amdgcn_s_barrier();

    for (int stp = 0; stp < nst; ++stp) {
        const int j0 = jbeg + stp * 16;
        const int cur = stp & 1;
        if (stp + 1 < nst) {                           // stage next (stays in flight)
#pragma unroll
            for (int itr = 0; itr < 4; ++itr) {
                int s = itr * 512 + t;
                int h = s >> 9, s2 = s & 511, jj = s2 & 15, kc = s2 >> 4;
                gld16(&Kb[((size_t)(b4 + h) * 1024 + j0 + 16 + jj) * 256 + kc * 8],
                      &Ks[cur ^ 1][s * 8]);
            }
        }
#pragma unroll
        for (int f = 0; f < 2; ++f) {
            if (j0 + 15 > i0w + f * 16) {              // per-wave causal skip
                f32x4 acc = {0.f, 0.f, 0.f, 0.f};
#pragma unroll
                for (int kk = 0; kk < 8; ++kk) {
                    bf16x8 bF = *(const bf16x8*)
                        &Ks[cur][(wh * 512 + (kk * 4 + lg4) * 16 + lr) * 8];
                    acc = __builtin_amdgcn_mfma_f32_16x16x32_bf16(aF[f][kk], bF, acc, 0, 0, 0);
                }
#pragma unroll
                for (int r = 0; r < 4; ++r) {
                    float e = __expf(acc[r] + cr[f][r]);
                    Pb[lr * 260 + (wi * 32 + f * 16 + lg4 * 4 + r) * 4 + wh] = f2bf(e);
                }
            }
        }
        asm volatile("s_waitcnt lgkmcnt(0)" ::: "memory");   // P visible; staging rides
        __builtin_amdgcn_sched_barrier(0);
        __builtin_amdgcn_s_barrier();
        // combine: each thread 2 outputs (i = iL, iL+32), one b64 P read each
        const int bitok = (vmbits >> ((j0 - jlo) >> 4)) & 1;
#pragma unroll
        for (int e2 = 0; e2 < 2; ++e2) {
            int i = iL + e2 * 32;
            int gi = i0blk + i, gj = j0 + jL;
            float o = -1.0e9f;
            if ((gj > gi) && bitok) {
                bf16x4 pv = *(const bf16x4*)&Pb[jL * 260 + i * 4];
                float s0 = bf2f(pv[0]) + bf2f(pv[1]) + bf2f(pv[2]) + bf2f(pv[3]);
                o = __logf(s0);
            }
            out[((size_t)(b * 1024) + gi) * 1024 + gj] = o;
        }
        asm volatile("s_waitcnt vmcnt(2)" ::: "memory");     // staging done; 2 stores ride
        __builtin_amdgcn_sched_barrier(0);
        __builtin_amdgcn_s_barrier();
    }
}

// ---------------------------------------------------------------------------
extern "C" void kernel_launch(void* const* d_in, const int* in_sizes, int n_in,
                              void* d_out, int out_size, void* d_ws, size_t ws_size,
                              hipStream_t stream) {
    const float* features = (const float*)d_in[0];
    const int*   vmask    = (const int*)d_in[1];
    const float* Wq       = (const float*)d_in[2];
    const float* bq       = (const float*)d_in[3];
    const float* Wk       = (const float*)d_in[4];
    const float* bk       = (const float*)d_in[5];
    const float* Wg       = (const float*)d_in[6];
    const float* bg       = (const float*)d_in[7];
    float* out = (float*)d_out;

    short* Xb = (short*)d_ws;                  // [8192][1024] bf16
    short* Wt = Xb + 8388608;                  // [2048][1024] bf16 (W^T, q then k)
    short* Qb = Wt + 2097152;                  // [32 bh][1024 i][256 d] bf16 (pre-scaled 1/16)
    short* Kb = Qb + 8388608;                  // [32 bh][1024 j][256 d] bf16
    float* lgA = (float*)(Kb + 8388608);       // [8192][4]
    float* Zp  = lgA + 32768;                  // [4 jt][32 bh][1024 i]
    float* cc  = Zp + 131072;                  // [32 bh][1024 i]

    k_cvt_x<<<4096, 256, 0, stream>>>(features, Xb);
    k_cvt_w<<<dim3(64, 32), dim3(32, 8), 0, stream>>>(Wq, Wk, Wt);
    k_gates<<<2048, 256, 0, stream>>>(features, Wg, bg, lgA);
    k_gemm<<<1024, 256, 0, stream>>>(Xb, Wt, bq, bk, Qb, Kb);
    k_stats<<<2048, 256, 0, stream>>>(Qb, Kb, vmask, Zp);
    k_c<<<128, 256, 0, stream>>>(lgA, Zp, cc);
    k_out<<<1024, 512, 0, stream>>>(Qb, Kb, vmask, cc, out);
}

// Round 4
// 151.347 us; speedup vs baseline: 1.3863x; 1.0931x over previous
//
#include <hip/hip_runtime.h>

// ---------------------------------------------------------------------------
// DagLinkExtractor: B=8, N=1024, HID=1024, NH=4, HD=256
// out[b,i,j] = logsumexp_h( s_masked[b,i,j,h] + c[b,i,h] )
//   s = (Q_h . K_h)/16  (1/16 folded into stored Q)
//   c[b,i,h] = log_gate[b,i,h] - log(sum_{valid j>i} exp(s))
//   masked / dead-row positions -> exactly -1e9f
// ---------------------------------------------------------------------------

typedef __attribute__((ext_vector_type(8))) short bf16x8;
typedef __attribute__((ext_vector_type(4))) short bf16x4;
typedef __attribute__((ext_vector_type(4))) float f32x4;

#define LB __launch_bounds__(256)

__device__ __forceinline__ short f2bf(float f) {
    unsigned u = __float_as_uint(f);
    u += 0x7fffu + ((u >> 16) & 1u);   // RNE
    return (short)(u >> 16);
}
__device__ __forceinline__ float bf2f(short s) {
    return __uint_as_float(((unsigned)(unsigned short)s) << 16);
}

__device__ __forceinline__ void gld16(const void* g, void* l) {
    __builtin_amdgcn_global_load_lds(
        (const __attribute__((address_space(1))) unsigned int*)g,
        (__attribute__((address_space(3))) unsigned int*)l, 16, 0, 0);
}

// ---- 1. features f32 -> bf16 ------------------------------------------------
__global__ LB void k_cvt_x(const float* __restrict__ src, short* __restrict__ dst) {
    int idx = blockIdx.x * 256 + threadIdx.x;
    const float4* s4 = (const float4*)src;
    float4 a = s4[idx * 2], b = s4[idx * 2 + 1];
    bf16x8 o;
    o[0] = f2bf(a.x); o[1] = f2bf(a.y); o[2] = f2bf(a.z); o[3] = f2bf(a.w);
    o[4] = f2bf(b.x); o[5] = f2bf(b.y); o[6] = f2bf(b.z); o[7] = f2bf(b.w);
    *(bf16x8*)&dst[idx * 8] = o;
}

// ---- 2. Wt[n][k] = W[k][n] (bf16), n<1024 -> Wq, else Wk --------------------
__global__ LB void k_cvt_w(const float* __restrict__ Wq, const float* __restrict__ Wk,
                           short* __restrict__ Wt) {
    __shared__ float tile[32][33];
    int n0 = blockIdx.x * 32, k0 = blockIdx.y * 32;
    const float* W = (n0 < 1024) ? Wq : Wk;
    int nb = n0 & 1023;
    int tx = threadIdx.x, ty = threadIdx.y;
#pragma unroll
    for (int jj = 0; jj < 4; ++jj) {
        int k = ty + jj * 8;
        tile[k][tx] = W[(size_t)(k0 + k) * 1024 + nb + tx];
    }
    __syncthreads();
#pragma unroll
    for (int jj = 0; jj < 4; ++jj) {
        int n = ty + jj * 8;
        Wt[(size_t)(n0 + n) * 1024 + k0 + tx] = f2bf(tile[tx][n]);
    }
}

// ---- 3. log_gates[b,i,h] ----------------------------------------------------
__global__ LB void k_gates(const float* __restrict__ feat, const float* __restrict__ Wg,
                           const float* __restrict__ bg, float* __restrict__ lgA) {
    int row = blockIdx.x * 4 + (threadIdx.x >> 6);
    int lane = threadIdx.x & 63;
    const float* f = feat + (size_t)row * 1024;
    float g0 = 0.f, g1 = 0.f, g2 = 0.f, g3 = 0.f;
#pragma unroll
    for (int t = 0; t < 16; ++t) {
        int k = lane + t * 64;
        float x = f[k];
        float4 w = *(const float4*)&Wg[k * 4];
        g0 += x * w.x; g1 += x * w.y; g2 += x * w.z; g3 += x * w.w;
    }
#pragma unroll
    for (int off = 32; off; off >>= 1) {
        g0 += __shfl_xor(g0, off); g1 += __shfl_xor(g1, off);
        g2 += __shfl_xor(g2, off); g3 += __shfl_xor(g3, off);
    }
    g0 += bg[0]; g1 += bg[1]; g2 += bg[2]; g3 += bg[3];
    float m = fmaxf(fmaxf(g0, g1), fmaxf(g2, g3));
    float s = __expf(g0 - m) + __expf(g1 - m) + __expf(g2 - m) + __expf(g3 - m);
    float ls = m + __logf(s);
    if (lane == 0) {
        float4 o = {g0 - ls, g1 - ls, g2 - ls, g3 - ls};
        *(float4*)&lgA[row * 4] = o;
    }
}

// ---- 4. GEMM 256x256 tile, BK=64, 4-quadrant-phase, counted vmcnt -----------
// Q = X@Wq+bq (scaled 1/16), K = X@Wk+bk; bf16 out in head layout.
// A/B LDS tiles [256 rows][64 k] bf16, read-swizzled slot ^= (row&7);
// global_load_lds dest linear, source pre-swizzled (rule: both-sides-or-neither).
// Staging of K-tile kt+1 spread 2 loads/phase:
//   ph0: A q0,q2 (rows 0-63 of each half)   ph1: B q0,q1
//   ph2: B q2,q3                            ph3: A q1,q3 (rows 64-127)
// Waits: end-ph1 vmcnt(4) (A-upper of CUR tile must land; 4 newer ride),
//        end-ph3 vmcnt(2) (next tile all but its A-upper pair; 2 ride).
__global__ __launch_bounds__(512, 2) void k_gemm(const short* __restrict__ Xb,
                                                 const short* __restrict__ Wt,
                                                 const float* __restrict__ bq,
                                                 const float* __restrict__ bk,
                                                 short* __restrict__ Qb,
                                                 short* __restrict__ Kb) {
    __shared__ short As[2][16384];                 // 2 x 32 KB: [256][64] bf16
    __shared__ short Bs[2][16384];
    const int t = threadIdx.x;
    const int lane = t & 63, wid = t >> 6;
    const int wr = wid >> 2, wc = wid & 3;         // 2 x 4 waves
    const int lr = lane & 15, lg4 = lane >> 4;
    // XCD-chunked: 256 wgs, 8 XCDs, 32/XCD; mt-major chunks (A slice L2-resident)
    const int wgid = (blockIdx.x & 7) * 32 + (blockIdx.x >> 3);
    const int mt = wgid >> 3, nt = wgid & 7;
    const int m0t = mt * 256, n0t = nt * 256;

    f32x4 acc[8][4] = {};

#define STAGE_A(q, k1, dst)                                                     \
    { int s_ = (q) * 512 + t; int tr_ = s_ >> 3, sl_ = s_ & 7;                  \
      gld16(&Xb[(size_t)(m0t + tr_) * 1024 + (k1) + ((sl_ ^ (tr_ & 7)) * 8)],   \
            &(dst)[s_ * 8]); }
#define STAGE_B(q, k1, dst)                                                     \
    { int s_ = (q) * 512 + t; int tr_ = s_ >> 3, sl_ = s_ & 7;                  \
      gld16(&Wt[(size_t)(n0t + tr_) * 1024 + (k1) + ((sl_ ^ (tr_ & 7)) * 8)],   \
            &(dst)[s_ * 8]); }

    // prologue: tile 0 fully staged, full drain once
    {
        short* Ad = As[0]; short* Bd = Bs[0];
        STAGE_A(0, 0, Ad); STAGE_A(1, 0, Ad); STAGE_A(2, 0, Ad); STAGE_A(3, 0, Ad);
        STAGE_B(0, 0, Bd); STAGE_B(1, 0, Bd); STAGE_B(2, 0, Bd); STAGE_B(3, 0, Bd);
    }
    asm volatile("s_waitcnt vmcnt(0)" ::: "memory");
    __builtin_amdgcn_sched_barrier(0);
    __builtin_amdgcn_s_barrier();

    for (int kt = 0; kt < 16; ++kt) {
        const int cur = kt & 1;
        const short* Ac = As[cur];
        const short* Bc = Bs[cur];
        short* Ad = As[cur ^ 1];
        short* Bd = Bs[cur ^ 1];
        const int k1 = (kt + 1) * 64;
        const int kb = kt * 64;                    // LDS holds this K range (layout only)
        (void)kb;
#pragma unroll
        for (int p = 0; p < 4; ++p) {
            const int mh = p >> 1, nh = p & 1;
            // 1) ds_read quadrant fragments (guaranteed by previous phase's barrier)
            bf16x8 aF[4][2], bF[2][2];
#pragma unroll
            for (int m = 0; m < 4; ++m)
#pragma unroll
                for (int ks = 0; ks < 2; ++ks) {
                    int row = wr * 128 + mh * 64 + m * 16 + lr;
                    aF[m][ks] = *(const bf16x8*)
                        &Ac[row * 64 + (((ks * 4 + lg4) ^ (lr & 7)) * 8)];
                }
#pragma unroll
            for (int n = 0; n < 2; ++n)
#pragma unroll
                for (int ks = 0; ks < 2; ++ks) {
                    int row = wc * 64 + (nh * 2 + n) * 16 + lr;
                    bF[n][ks] = *(const bf16x8*)
                        &Bc[row * 64 + (((ks * 4 + lg4) ^ (lr & 7)) * 8)];
                }
            // 2) stage 2 half-tile loads of tile kt+1
            if (kt < 15) {
                if (p == 0)      { STAGE_A(0, k1, Ad); STAGE_A(2, k1, Ad); }
                else if (p == 1) { STAGE_B(0, k1, Bd); STAGE_B(1, k1, Bd); }
                else if (p == 2) { STAGE_B(2, k1, Bd); STAGE_B(3, k1, Bd); }
                else             { STAGE_A(1, k1, Ad); STAGE_A(3, k1, Ad); }
            }
            // 3) counted waits (never 0 in steady state)
            if (p == 1) {
                if (kt < 15) asm volatile("s_waitcnt vmcnt(4)" ::: "memory");
                else         asm volatile("s_waitcnt vmcnt(0)" ::: "memory");
            } else if (p == 3 && kt < 15) {
                asm volatile("s_waitcnt vmcnt(2)" ::: "memory");
            }
            __builtin_amdgcn_sched_barrier(0);
            __builtin_amdgcn_s_barrier();
            asm volatile("s_waitcnt lgkmcnt(0)" ::: "memory");
            __builtin_amdgcn_sched_barrier(0);
            // 4) 16 MFMA (one C-quadrant x K=64)
            __builtin_amdgcn_s_setprio(1);
#pragma unroll
            for (int ks = 0; ks < 2; ++ks)
#pragma unroll
                for (int m = 0; m < 4; ++m)
#pragma unroll
                    for (int n = 0; n < 2; ++n)
                        acc[mh * 4 + m][nh * 2 + n] =
                            __builtin_amdgcn_mfma_f32_16x16x32_bf16(
                                aF[m][ks], bF[n][ks], acc[mh * 4 + m][nh * 2 + n],
                                0, 0, 0);
            __builtin_amdgcn_s_setprio(0);
        }
    }
#undef STAGE_A
#undef STAGE_B

    // epilogue: bias + scale + bf16 + head-layout scatter
#pragma unroll
    for (int mf = 0; mf < 8; ++mf) {
#pragma unroll
        for (int nf = 0; nf < 4; ++nf) {
            int col = n0t + wc * 64 + nf * 16 + lr;
            float bias = (col < 1024) ? bq[col] : bk[col - 1024];
            float scale = (col < 1024) ? 0.0625f : 1.0f;
            short* dst = (col < 1024) ? Qb : Kb;
            int h = (col >> 8) & 3, d = col & 255;
#pragma unroll
            for (int r = 0; r < 4; ++r) {
                int rowg = m0t + wr * 128 + mf * 16 + lg4 * 4 + r;
                int b_ = rowg >> 10, i_ = rowg & 1023;
                float v = (acc[mf][nf][r] + bias) * scale;
                dst[((size_t)(b_ * 4 + h) * 1024 + i_) * 256 + d] = f2bf(v);
            }
        }
    }
}

// ---- 5. pass 1: partial Z[jt][bh,i] = sum_{valid j>i, j in jt} exp(s) -------
// grid 2048 (XCD-chunked), 256 thr; double-buffered K staging
__global__ __launch_bounds__(256, 4) void k_stats(const short* __restrict__ Qb,
                                                  const short* __restrict__ Kb,
                                                  const int* __restrict__ vm,
                                                  float* __restrict__ Zp) {
    __shared__ short Ks[2][4096];                      // 2 x 8 KB, d-chunk-major
    const int t = threadIdx.x, lane = t & 63, wid = t >> 6;
    const int wgid = ((blockIdx.x & 7) << 8) | (blockIdx.x >> 3);  // XCD-chunked
    const int jt = wgid & 3;
    const int it = (wgid >> 2) & 15;
    const int bh = wgid >> 6;
    const int b = bh >> 2;
    const int i0blk = it * 64;
    const int i0 = i0blk + wid * 16;
    const int lr = lane & 15, lg4 = lane >> 4;
    const int jlo = jt * 256, jhi = jlo + 256;
    const int jstart = (jlo > i0blk) ? jlo : i0blk;
    float Z[4] = {0.f, 0.f, 0.f, 0.f};
    if (jstart < jhi) {
        bf16x8 aF[8];
        const short* qrow = &Qb[((size_t)bh * 1024 + i0 + lr) * 256];
#pragma unroll
        for (int kk = 0; kk < 8; ++kk) aF[kk] = *(const bf16x8*)&qrow[kk * 32 + lg4 * 8];
#pragma unroll
        for (int kk = 0; kk < 8; ++kk) asm volatile("" : "+v"(aF[kk]));
        unsigned vmbits = 0;
#pragma unroll
        for (int st = 0; st < 16; ++st)
            vmbits |= (vm[b * 1024 + jlo + st * 16 + lr] ? 1u : 0u) << st;
#pragma unroll
        for (int itr = 0; itr < 2; ++itr) {            // prologue stage -> buf 0
            int s = itr * 256 + t, jj = s & 15, kc = s >> 4;
            gld16(&Kb[((size_t)bh * 1024 + jstart + jj) * 256 + kc * 8], &Ks[0][s * 8]);
        }
        asm volatile("s_waitcnt vmcnt(0)" ::: "memory");
        __builtin_amdgcn_sched_barrier(0);
        __builtin_amdgcn_s_barrier();
        const int nst = (jhi - jstart) >> 4;
        for (int stp = 0; stp < nst; ++stp) {
            const int j0 = jstart + stp * 16;
            const int cur = stp & 1;
            if (stp + 1 < nst) {
#pragma unroll
                for (int itr = 0; itr < 2; ++itr) {
                    int s = itr * 256 + t, jj = s & 15, kc = s >> 4;
                    gld16(&Kb[((size_t)bh * 1024 + j0 + 16 + jj) * 256 + kc * 8],
                          &Ks[cur ^ 1][s * 8]);
                }
            }
            if (j0 + 15 > i0) {                        // per-wave skip (no barrier inside)
                f32x4 acc = {0.f, 0.f, 0.f, 0.f};
#pragma unroll
                for (int kk = 0; kk < 8; ++kk) {
                    bf16x8 bF = *(const bf16x8*)&Ks[cur][((kk * 4 + lg4) * 16 + lr) * 8];
                    acc = __builtin_amdgcn_mfma_f32_16x16x32_bf16(aF[kk], bF, acc, 0, 0, 0);
                }
                const int okj = (vmbits >> ((j0 - jlo) >> 4)) & 1;
                const int j = j0 + lr;
#pragma unroll
                for (int r = 0; r < 4; ++r) {
                    int ir = i0 + lg4 * 4 + r;
                    Z[r] += (okj && (j > ir)) ? __expf(acc[r]) : 0.f;
                }
            }
            asm volatile("s_waitcnt vmcnt(0)" ::: "memory");
            __builtin_amdgcn_sched_barrier(0);
            __builtin_amdgcn_s_barrier();
        }
    }
#pragma unroll
    for (int off = 1; off < 16; off <<= 1) {
#pragma unroll
        for (int r = 0; r < 4; ++r) Z[r] += __shfl_xor(Z[r], off);
    }
    if (lr < 4) Zp[jt * 32768 + bh * 1024 + i0 + lg4 * 4 + lr] = Z[lr];
}

// ---- 6. c[bh,i] = lg - log(sum_jt Zp) ---------------------------------------
__global__ LB void k_c(const float* __restrict__ lgA, const float* __restrict__ Zp,
                       float* __restrict__ cc) {
    int idx = blockIdx.x * 256 + threadIdx.x;          // 32768
    int bh = idx >> 10, i = idx & 1023;
    int b = bh >> 2, h = bh & 3;
    float Zv = Zp[idx] + Zp[32768 + idx] + Zp[65536 + idx] + Zp[98304 + idx];
    float lgv = lgA[(b * 1024 + i) * 4 + h];
    cc[idx] = lgv - (Zv > 0.f ? __logf(Zv) : 0.f);
}

// ---- 7. pass 2: out[b,i,j] --------------------------------------------------
// grid 1024 (XCD-chunked: each XCD owns one b), 512 thr = 4 heads x 2 i-halves
__global__ __launch_bounds__(512, 4) void k_out(const short* __restrict__ Qb,
                                                const short* __restrict__ Kb,
                                                const int* __restrict__ vm,
                                                const float* __restrict__ cc,
                                                float* __restrict__ out) {
    __shared__ short Ks[2][16384];                     // 2 x 32 KB, per-head d-chunk-major
    __shared__ __align__(16) short Pb[16 * 260];       // [j][i][4h] bf16 + pad, 8.1 KB
    const int t = threadIdx.x, lane = t & 63, wid = t >> 6;
    const int wh = wid & 3, wi = wid >> 2;
    const int wgid = ((blockIdx.x & 7) << 7) | (blockIdx.x >> 3);  // XCD-chunked
    const int it = wgid & 15;
    const int jt = (wgid >> 4) & 7;
    const int b = wgid >> 7;
    const int i0blk = it * 64, jlo = jt * 128;
    const int b4 = b * 4;

    int jbeg = (i0blk > jlo) ? i0blk : jlo;            // fully-masked prefix -> fill
    if (jbeg > jlo + 128) jbeg = jlo + 128;
    {
        const float4 m4 = {-1.0e9f, -1.0e9f, -1.0e9f, -1.0e9f};
        const int r = t >> 3, cg = t & 7;
        for (int c0 = jlo; c0 < jbeg; c0 += 64) {
            float* p = &out[((size_t)(b * 1024) + i0blk + r) * 1024 + c0 + cg * 8];
            *(float4*)p = m4;
            *(float4*)(p + 4) = m4;
        }
    }
    if (jbeg == jlo + 128) return;                     // block-uniform, pre-barrier
    const int nst = (jlo + 128 - jbeg) >> 4;

    const int lr = lane & 15, lg4 = lane >> 4;
    const int i0w = i0blk + wi * 32;
    bf16x8 aF[2][8];
    float cr[2][4];
#pragma unroll
    for (int f = 0; f < 2; ++f) {
        const short* qrow = &Qb[((size_t)(b4 + wh) * 1024 + i0w + f * 16 + lr) * 256];
#pragma unroll
        for (int kk = 0; kk < 8; ++kk) aF[f][kk] = *(const bf16x8*)&qrow[kk * 32 + lg4 * 8];
#pragma unroll
        for (int r = 0; r < 4; ++r)
            cr[f][r] = cc[(b4 + wh) * 1024 + i0w + f * 16 + lg4 * 4 + r];
    }
#pragma unroll
    for (int kk = 0; kk < 8; ++kk)
        asm volatile("" : "+v"(aF[0][kk]), "+v"(aF[1][kk]));   // pin: no remat

    const int jL = t & 15, iL = t >> 4;
    unsigned vmbits = 0;
#pragma unroll
    for (int st = 0; st < 8; ++st)
        vmbits |= (vm[b * 1024 + jlo + st * 16 + jL] ? 1u : 0u) << st;

#pragma unroll
    for (int itr = 0; itr < 4; ++itr) {                // prologue stage -> buf 0
        int s = itr * 512 + t;
        int h = s >> 9, s2 = s & 511, jj = s2 & 15, kc = s2 >> 4;
        gld16(&Kb[((size_t)(b4 + h) * 1024 + jbeg + jj) * 256 + kc * 8], &Ks[0][s * 8]);
    }
    asm volatile("s_waitcnt vmcnt(0)" ::: "memory");
    __builtin_amdgcn_sched_barrier(0);
    __builtin_amdgcn_s_barrier();

    for (int stp = 0; stp < nst; ++stp) {
        const int j0 = jbeg + stp * 16;
        const int cur = stp & 1;
        if (stp + 1 < nst) {                           // stage next (stays in flight)
#pragma unroll
            for (int itr = 0; itr < 4; ++itr) {
                int s = itr * 512 + t;
                int h = s >> 9, s2 = s & 511, jj = s2 & 15, kc = s2 >> 4;
                gld16(&Kb[((size_t)(b4 + h) * 1024 + j0 + 16 + jj) * 256 + kc * 8],
                      &Ks[cur ^ 1][s * 8]);
            }
        }
#pragma unroll
        for (int f = 0; f < 2; ++f) {
            if (j0 + 15 > i0w + f * 16) {              // per-wave causal skip
                f32x4 acc = {0.f, 0.f, 0.f, 0.f};
#pragma unroll
                for (int kk = 0; kk < 8; ++kk) {
                    bf16x8 bF = *(const bf16x8*)
                        &Ks[cur][(wh * 512 + (kk * 4 + lg4) * 16 + lr) * 8];
                    acc = __builtin_amdgcn_mfma_f32_16x16x32_bf16(aF[f][kk], bF, acc, 0, 0, 0);
                }
#pragma unroll
                for (int r = 0; r < 4; ++r) {
                    float e = __expf(acc[r] + cr[f][r]);
                    Pb[lr * 260 + (wi * 32 + f * 16 + lg4 * 4 + r) * 4 + wh] = f2bf(e);
                }
            }
        }
        asm volatile("s_waitcnt lgkmcnt(0)" ::: "memory");   // P visible; staging rides
        __builtin_amdgcn_sched_barrier(0);
        __builtin_amdgcn_s_barrier();
        // combine: each thread 2 outputs (i = iL, iL+32), one b64 P read each
        const int bitok = (vmbits >> ((j0 - jlo) >> 4)) & 1;
#pragma unroll
        for (int e2 = 0; e2 < 2; ++e2) {
            int i = iL + e2 * 32;
            int gi = i0blk + i, gj = j0 + jL;
            float o = -1.0e9f;
            if ((gj > gi) && bitok) {
                bf16x4 pv = *(const bf16x4*)&Pb[jL * 260 + i * 4];
                float s0 = bf2f(pv[0]) + bf2f(pv[1]) + bf2f(pv[2]) + bf2f(pv[3]);
                o = __logf(s0);
            }
            out[((size_t)(b * 1024) + gi) * 1024 + gj] = o;
        }
        asm volatile("s_waitcnt vmcnt(2)" ::: "memory");     // staging done; 2 stores ride
        __builtin_amdgcn_sched_barrier(0);
        __builtin_amdgcn_s_barrier();
    }
}

// ---------------------------------------------------------------------------
extern "C" void kernel_launch(void* const* d_in, const int* in_sizes, int n_in,
                              void* d_out, int out_size, void* d_ws, size_t ws_size,
                              hipStream_t stream) {
    const float* features = (const float*)d_in[0];
    const int*   vmask    = (const int*)d_in[1];
    const float* Wq       = (const float*)d_in[2];
    const float* bq       = (const float*)d_in[3];
    const float* Wk       = (const float*)d_in[4];
    const float* bk       = (const float*)d_in[5];
    const float* Wg       = (const float*)d_in[6];
    const float* bg       = (const float*)d_in[7];
    float* out = (float*)d_out;

    short* Xb = (short*)d_ws;                  // [8192][1024] bf16
    short* Wt = Xb + 8388608;                  // [2048][1024] bf16 (W^T, q then k)
    short* Qb = Wt + 2097152;                  // [32 bh][1024 i][256 d] bf16 (pre-scaled 1/16)
    short* Kb = Qb + 8388608;                  // [32 bh][1024 j][256 d] bf16
    float* lgA = (float*)(Kb + 8388608);       // [8192][4]
    float* Zp  = lgA + 32768;                  // [4 jt][32 bh][1024 i]
    float* cc  = Zp + 131072;                  // [32 bh][1024 i]

    k_cvt_x<<<4096, 256, 0, stream>>>(features, Xb);
    k_cvt_w<<<dim3(64, 32), dim3(32, 8), 0, stream>>>(Wq, Wk, Wt);
    k_gates<<<2048, 256, 0, stream>>>(features, Wg, bg, lgA);
    k_gemm<<<256, 512, 0, stream>>>(Xb, Wt, bq, bk, Qb, Kb);
    k_stats<<<2048, 256, 0, stream>>>(Qb, Kb, vmask, Zp);
    k_c<<<128, 256, 0, stream>>>(lgA, Zp, cc);
    k_out<<<1024, 512, 0, stream>>>(Qb, Kb, vmask, cc, out);
}

// Round 5
// 113.952 us; speedup vs baseline: 1.8413x; 1.3282x over previous
//
#include <hip/hip_runtime.h>

// ---------------------------------------------------------------------------
// DagLinkExtractor: B=8, N=1024, HID=1024, NH=4, HD=256
// out[b,i,j] = log Σ_h P[b,i,j,h]·ec[b,h,i]   (alive), else -1e9
//   P = exp(s), s = (Q_h . K_h)/16  (1/16 folded into stored Q)
//   ec[b,h,i] = exp(log_gate) / Z,  Z = Σ_{valid j>i} exp(s)
// Single score pass (k_scores) materializes P (bf16, 67MB) + Z partials.
// ---------------------------------------------------------------------------

typedef __attribute__((ext_vector_type(8))) short bf16x8;
typedef __attribute__((ext_vector_type(4))) short bf16x4;
typedef __attribute__((ext_vector_type(4))) float f32x4;

#define LB __launch_bounds__(256)

__device__ __forceinline__ short f2bf(float f) {
    unsigned u = __float_as_uint(f);
    u += 0x7fffu + ((u >> 16) & 1u);   // RNE
    return (short)(u >> 16);
}
__device__ __forceinline__ float bf2f(short s) {
    return __uint_as_float(((unsigned)(unsigned short)s) << 16);
}

__device__ __forceinline__ void gld16(const void* g, void* l) {
    __builtin_amdgcn_global_load_lds(
        (const __attribute__((address_space(1))) unsigned int*)g,
        (__attribute__((address_space(3))) unsigned int*)l, 16, 0, 0);
}

// ---- 1. fused: Xb = bf16(features), lgA = log_softmax(features@Wg+bg) -------
__global__ LB void k_prep(const float* __restrict__ feat, const float* __restrict__ Wg,
                          const float* __restrict__ bg, short* __restrict__ Xb,
                          float* __restrict__ lgA) {
    int row = blockIdx.x * 4 + (threadIdx.x >> 6);
    int lane = threadIdx.x & 63;
    const float* f = feat + (size_t)row * 1024;
    float g0 = 0.f, g1 = 0.f, g2 = 0.f, g3 = 0.f;
#pragma unroll
    for (int tt = 0; tt < 4; ++tt) {
        int k = tt * 256 + lane * 4;
        float4 x = *(const float4*)&f[k];
        float4 w0 = *(const float4*)&Wg[(k + 0) * 4];
        float4 w1 = *(const float4*)&Wg[(k + 1) * 4];
        float4 w2 = *(const float4*)&Wg[(k + 2) * 4];
        float4 w3 = *(const float4*)&Wg[(k + 3) * 4];
        g0 += x.x * w0.x + x.y * w1.x + x.z * w2.x + x.w * w3.x;
        g1 += x.x * w0.y + x.y * w1.y + x.z * w2.y + x.w * w3.y;
        g2 += x.x * w0.z + x.y * w1.z + x.z * w2.z + x.w * w3.z;
        g3 += x.x * w0.w + x.y * w1.w + x.z * w2.w + x.w * w3.w;
        bf16x4 xv;
        xv[0] = f2bf(x.x); xv[1] = f2bf(x.y); xv[2] = f2bf(x.z); xv[3] = f2bf(x.w);
        *(bf16x4*)&Xb[(size_t)row * 1024 + k] = xv;
    }
#pragma unroll
    for (int off = 32; off; off >>= 1) {
        g0 += __shfl_xor(g0, off); g1 += __shfl_xor(g1, off);
        g2 += __shfl_xor(g2, off); g3 += __shfl_xor(g3, off);
    }
    g0 += bg[0]; g1 += bg[1]; g2 += bg[2]; g3 += bg[3];
    float m = fmaxf(fmaxf(g0, g1), fmaxf(g2, g3));
    float s = __expf(g0 - m) + __expf(g1 - m) + __expf(g2 - m) + __expf(g3 - m);
    float ls = m + __logf(s);
    if (lane == 0) {
        float4 o = {g0 - ls, g1 - ls, g2 - ls, g3 - ls};
        *(float4*)&lgA[row * 4] = o;
    }
}

// ---- 2. Wt[n][k] = W[k][n] (bf16), n<1024 -> Wq, else Wk --------------------
__global__ LB void k_cvt_w(const float* __restrict__ Wq, const float* __restrict__ Wk,
                           short* __restrict__ Wt) {
    __shared__ float tile[32][33];
    int n0 = blockIdx.x * 32, k0 = blockIdx.y * 32;
    const float* W = (n0 < 1024) ? Wq : Wk;
    int nb = n0 & 1023;
    int tx = threadIdx.x, ty = threadIdx.y;
#pragma unroll
    for (int jj = 0; jj < 4; ++jj) {
        int k = ty + jj * 8;
        tile[k][tx] = W[(size_t)(k0 + k) * 1024 + nb + tx];
    }
    __syncthreads();
#pragma unroll
    for (int jj = 0; jj < 4; ++jj) {
        int n = ty + jj * 8;
        Wt[(size_t)(n0 + n) * 1024 + k0 + tx] = f2bf(tile[tx][n]);
    }
}

// ---- 3. GEMM 256x256 tile, BK=64, 4-quadrant-phase, counted vmcnt -----------
__global__ __launch_bounds__(512, 2) void k_gemm(const short* __restrict__ Xb,
                                                 const short* __restrict__ Wt,
                                                 const float* __restrict__ bq,
                                                 const float* __restrict__ bk,
                                                 short* __restrict__ Qb,
                                                 short* __restrict__ Kb) {
    __shared__ short As[2][16384];                 // 2 x 32 KB: [256][64] bf16
    __shared__ short Bs[2][16384];
    const int t = threadIdx.x;
    const int lane = t & 63, wid = t >> 6;
    const int wr = wid >> 2, wc = wid & 3;         // 2 x 4 waves
    const int lr = lane & 15, lg4 = lane >> 4;
    const int wgid = (blockIdx.x & 7) * 32 + (blockIdx.x >> 3);
    const int mt = wgid >> 3, nt = wgid & 7;
    const int m0t = mt * 256, n0t = nt * 256;

    f32x4 acc[8][4] = {};

#define STAGE_A(q, k1, dst)                                                     \
    { int s_ = (q) * 512 + t; int tr_ = s_ >> 3, sl_ = s_ & 7;                  \
      gld16(&Xb[(size_t)(m0t + tr_) * 1024 + (k1) + ((sl_ ^ (tr_ & 7)) * 8)],   \
            &(dst)[s_ * 8]); }
#define STAGE_B(q, k1, dst)                                                     \
    { int s_ = (q) * 512 + t; int tr_ = s_ >> 3, sl_ = s_ & 7;                  \
      gld16(&Wt[(size_t)(n0t + tr_) * 1024 + (k1) + ((sl_ ^ (tr_ & 7)) * 8)],   \
            &(dst)[s_ * 8]); }

    {
        short* Ad = As[0]; short* Bd = Bs[0];
        STAGE_A(0, 0, Ad); STAGE_A(1, 0, Ad); STAGE_A(2, 0, Ad); STAGE_A(3, 0, Ad);
        STAGE_B(0, 0, Bd); STAGE_B(1, 0, Bd); STAGE_B(2, 0, Bd); STAGE_B(3, 0, Bd);
    }
    asm volatile("s_waitcnt vmcnt(0)" ::: "memory");
    __builtin_amdgcn_sched_barrier(0);
    __builtin_amdgcn_s_barrier();

    for (int kt = 0; kt < 16; ++kt) {
        const int cur = kt & 1;
        const short* Ac = As[cur];
        const short* Bc = Bs[cur];
        short* Ad = As[cur ^ 1];
        short* Bd = Bs[cur ^ 1];
        const int k1 = (kt + 1) * 64;
#pragma unroll
        for (int p = 0; p < 4; ++p) {
            const int mh = p >> 1, nh = p & 1;
            bf16x8 aF[4][2], bF[2][2];
#pragma unroll
            for (int m = 0; m < 4; ++m)
#pragma unroll
                for (int ks = 0; ks < 2; ++ks) {
                    int row = wr * 128 + mh * 64 + m * 16 + lr;
                    aF[m][ks] = *(const bf16x8*)
                        &Ac[row * 64 + (((ks * 4 + lg4) ^ (lr & 7)) * 8)];
                }
#pragma unroll
            for (int n = 0; n < 2; ++n)
#pragma unroll
                for (int ks = 0; ks < 2; ++ks) {
                    int row = wc * 64 + (nh * 2 + n) * 16 + lr;
                    bF[n][ks] = *(const bf16x8*)
                        &Bc[row * 64 + (((ks * 4 + lg4) ^ (lr & 7)) * 8)];
                }
            if (kt < 15) {
                if (p == 0)      { STAGE_A(0, k1, Ad); STAGE_A(2, k1, Ad); }
                else if (p == 1) { STAGE_B(0, k1, Bd); STAGE_B(1, k1, Bd); }
                else if (p == 2) { STAGE_B(2, k1, Bd); STAGE_B(3, k1, Bd); }
                else             { STAGE_A(1, k1, Ad); STAGE_A(3, k1, Ad); }
            }
            if (p == 1) {
                if (kt < 15) asm volatile("s_waitcnt vmcnt(4)" ::: "memory");
                else         asm volatile("s_waitcnt vmcnt(0)" ::: "memory");
            } else if (p == 3 && kt < 15) {
                asm volatile("s_waitcnt vmcnt(2)" ::: "memory");
            }
            __builtin_amdgcn_sched_barrier(0);
            __builtin_amdgcn_s_barrier();
            asm volatile("s_waitcnt lgkmcnt(0)" ::: "memory");
            __builtin_amdgcn_sched_barrier(0);
            __builtin_amdgcn_s_setprio(1);
#pragma unroll
            for (int ks = 0; ks < 2; ++ks)
#pragma unroll
                for (int m = 0; m < 4; ++m)
#pragma unroll
                    for (int n = 0; n < 2; ++n)
                        acc[mh * 4 + m][nh * 2 + n] =
                            __builtin_amdgcn_mfma_f32_16x16x32_bf16(
                                aF[m][ks], bF[n][ks], acc[mh * 4 + m][nh * 2 + n],
                                0, 0, 0);
            __builtin_amdgcn_s_setprio(0);
        }
    }
#undef STAGE_A
#undef STAGE_B

#pragma unroll
    for (int mf = 0; mf < 8; ++mf) {
#pragma unroll
        for (int nf = 0; nf < 4; ++nf) {
            int col = n0t + wc * 64 + nf * 16 + lr;
            float bias = (col < 1024) ? bq[col] : bk[col - 1024];
            float scale = (col < 1024) ? 0.0625f : 1.0f;
            short* dst = (col < 1024) ? Qb : Kb;
            int h = (col >> 8) & 3, d = col & 255;
#pragma unroll
            for (int r = 0; r < 4; ++r) {
                int rowg = m0t + wr * 128 + mf * 16 + lg4 * 4 + r;
                int b_ = rowg >> 10, i_ = rowg & 1023;
                float v = (acc[mf][nf][r] + bias) * scale;
                dst[((size_t)(b_ * 4 + h) * 1024 + i_) * 256 + d] = f2bf(v);
            }
        }
    }
}

// ---- 4. single score pass: Pe[b][i][j][4h] = bf16(exp(s)), Z partials -------
// grid 512 (XCD-chunked, one b per XCD), 512 thr = 4 heads x 2 i-halves.
// K dbuf + Pb dbuf, ONE barrier/step; P-store pipelined one step behind.
__global__ __launch_bounds__(512, 4) void k_scores(const short* __restrict__ Qb,
                                                   const short* __restrict__ Kb,
                                                   const int* __restrict__ vm,
                                                   short* __restrict__ Pe,
                                                   float* __restrict__ Zp) {
    __shared__ short Ks[2][16384];                 // 2 x 32 KB per-head d-chunk-major
    __shared__ short Pb[2][4096];                  // 2 x 8 KB: [64i][16j][4h] bf16
    const int t = threadIdx.x, lane = t & 63, wid = t >> 6;
    const int wh = wid & 3, wi = wid >> 2;
    const int wgid = (blockIdx.x & 7) * 64 + (blockIdx.x >> 3);    // XCD-chunked
    const int b = wgid >> 6;
    const int it = (wgid >> 2) & 15;
    const int jt = wgid & 3;
    const int i0blk = it * 64, jlo = jt * 256, jhi = jlo + 256;
    const int b4 = b * 4;
    int jbeg = (jlo > i0blk) ? jlo : i0blk;

    if (jbeg >= jhi) {                             // no alive j here: zero Z, exit
        if (t < 256)
            Zp[jt * 32768 + (b4 + (t >> 6)) * 1024 + i0blk + (t & 63)] = 0.f;
        return;
    }
    const int nst = (jhi - jbeg) >> 4;
    const int lr = lane & 15, lg4 = lane >> 4;
    const int i0w = i0blk + wi * 32;

    bf16x8 aF[2][8];
#pragma unroll
    for (int f = 0; f < 2; ++f) {
        const short* qrow = &Qb[((size_t)(b4 + wh) * 1024 + i0w + f * 16 + lr) * 256];
#pragma unroll
        for (int kk = 0; kk < 8; ++kk) aF[f][kk] = *(const bf16x8*)&qrow[kk * 32 + lg4 * 8];
    }
#pragma unroll
    for (int kk = 0; kk < 8; ++kk)
        asm volatile("" : "+v"(aF[0][kk]), "+v"(aF[1][kk]));   // pin: no remat

    unsigned vmbits = 0;
#pragma unroll
    for (int st = 0; st < 16; ++st)
        vmbits |= (vm[b * 1024 + jlo + st * 16 + lr] ? 1u : 0u) << st;

    float Z[2][4] = {};

#pragma unroll
    for (int itr = 0; itr < 4; ++itr) {            // prologue stage -> buf 0
        int s = itr * 512 + t;
        int h = s >> 9, s2 = s & 511, jj = s2 & 15, kc = s2 >> 4;
        gld16(&Kb[((size_t)(b4 + h) * 1024 + jbeg + jj) * 256 + kc * 8], &Ks[0][s * 8]);
    }
    asm volatile("s_waitcnt vmcnt(0)" ::: "memory");
    __builtin_amdgcn_sched_barrier(0);
    __builtin_amdgcn_s_barrier();

    const int prow = t >> 3, pseg = t & 7;         // P-store mapping: 16B/thread

    for (int stp = 0; stp < nst; ++stp) {
        const int j0 = jbeg + stp * 16;
        const int cur = stp & 1;
        if (stp + 1 < nst) {                       // stage next K tile
#pragma unroll
            for (int itr = 0; itr < 4; ++itr) {
                int s = itr * 512 + t;
                int h = s >> 9, s2 = s & 511, jj = s2 & 15, kc = s2 >> 4;
                gld16(&Kb[((size_t)(b4 + h) * 1024 + j0 + 16 + jj) * 256 + kc * 8],
                      &Ks[cur ^ 1][s * 8]);
            }
        }
        if (stp > 0) {                             // store previous P tile (coalesced)
            bf16x8 v = *(const bf16x8*)&Pb[cur ^ 1][prow * 64 + pseg * 8];
            *(bf16x8*)&Pe[((size_t)((b << 10) + i0blk + prow) * 1024 + (j0 - 16)) * 4
                          + pseg * 8] = v;
        }
#pragma unroll
        for (int f = 0; f < 2; ++f) {
            if (j0 + 15 > i0w + f * 16) {          // wave-uniform causal skip
                f32x4 acc = {0.f, 0.f, 0.f, 0.f};
#pragma unroll
                for (int kk = 0; kk < 8; ++kk) {
                    bf16x8 bF = *(const bf16x8*)
                        &Ks[cur][(wh * 512 + (kk * 4 + lg4) * 16 + lr) * 8];
                    acc = __builtin_amdgcn_mfma_f32_16x16x32_bf16(aF[f][kk], bF, acc, 0, 0, 0);
                }
                const int okj = (vmbits >> ((j0 - jlo) >> 4)) & 1;
                const int j = j0 + lr;
#pragma unroll
                for (int r = 0; r < 4; ++r) {
                    float e = __expf(acc[r]);
                    int irow = wi * 32 + f * 16 + lg4 * 4 + r;
                    Pb[cur][(irow * 16 + lr) * 4 + wh] = f2bf(e);
                    Z[f][r] += (okj && (j > i0w + f * 16 + lg4 * 4 + r)) ? e : 0.f;
                }
            }
        }
        asm volatile("s_waitcnt lgkmcnt(0)" ::: "memory");
        __builtin_amdgcn_sched_barrier(0);
        asm volatile("s_waitcnt vmcnt(0)" ::: "memory");
        __builtin_amdgcn_sched_barrier(0);
        __builtin_amdgcn_s_barrier();
    }
    {                                              // epilogue: store last P tile
        const int cur = (nst - 1) & 1;
        const int j0p = jbeg + (nst - 1) * 16;
        bf16x8 v = *(const bf16x8*)&Pb[cur][prow * 64 + pseg * 8];
        *(bf16x8*)&Pe[((size_t)((b << 10) + i0blk + prow) * 1024 + j0p) * 4
                      + pseg * 8] = v;
    }
    // Z reduce over the 16 j-lanes, write partials
#pragma unroll
    for (int f = 0; f < 2; ++f)
#pragma unroll
        for (int r = 0; r < 4; ++r)
#pragma unroll
            for (int off = 1; off < 16; off <<= 1)
                Z[f][r] += __shfl_xor(Z[f][r], off);
    if (lr < 4) {
#pragma unroll
        for (int f = 0; f < 2; ++f) {
            float zv = (lr == 0) ? Z[f][0] : (lr == 1) ? Z[f][1]
                     : (lr == 2) ? Z[f][2] : Z[f][3];
            Zp[jt * 32768 + (b4 + wh) * 1024 + i0w + f * 16 + lg4 * 4 + lr] = zv;
        }
    }
}

// ---- 5. ecT[b][i][4h] = exp(lg) / Z  (Z==0 -> 0, row dead) ------------------
__global__ LB void k_c(const float* __restrict__ lgA, const float* __restrict__ Zp,
                       float* __restrict__ ecT) {
    int idx = blockIdx.x * 256 + threadIdx.x;      // 8192 = (b,i)
    int b = idx >> 10, i = idx & 1023;
    float4 lg = *(const float4*)&lgA[idx * 4];
    float4 o;
#pragma unroll
    for (int h = 0; h < 4; ++h) {
        int base = (b * 4 + h) * 1024 + i;
        float Zv = Zp[base] + Zp[32768 + base] + Zp[65536 + base] + Zp[98304 + base];
        float lgv = (h == 0) ? lg.x : (h == 1) ? lg.y : (h == 2) ? lg.z : lg.w;
        float e = (Zv > 0.f) ? __expf(lgv) / Zv : 0.f;
        if (h == 0) o.x = e; else if (h == 1) o.y = e; else if (h == 2) o.z = e; else o.w = e;
    }
    *(float4*)&ecT[idx * 4] = o;
}

// ---- 6. streaming epilogue: out = alive ? log(dot(P, ec)) : -1e9 ------------
// grid 8192 = (b,i); 256 thr x 4 j each
__global__ LB void k_final(const short* __restrict__ Pe, const int* __restrict__ vm,
                           const float* __restrict__ ecT, float* __restrict__ out) {
    const int blk = blockIdx.x;                    // b*1024 + i
    const int b = blk >> 10, i = blk & 1023;
    const int j0 = threadIdx.x * 4;
    float4 o = {-1.0e9f, -1.0e9f, -1.0e9f, -1.0e9f};
    if (j0 + 3 > i) {
        float4 ec = *(const float4*)&ecT[blk * 4];
        int4 v4 = *(const int4*)&vm[b * 1024 + j0];
        const short* pp = &Pe[((size_t)blk * 1024 + j0) * 4];
        bf16x8 p01 = *(const bf16x8*)pp;
        bf16x8 p23 = *(const bf16x8*)(pp + 8);
        float s0 = bf2f(p01[0]) * ec.x + bf2f(p01[1]) * ec.y
                 + bf2f(p01[2]) * ec.z + bf2f(p01[3]) * ec.w;
        float s1 = bf2f(p01[4]) * ec.x + bf2f(p01[5]) * ec.y
                 + bf2f(p01[6]) * ec.z + bf2f(p01[7]) * ec.w;
        float s2 = bf2f(p23[0]) * ec.x + bf2f(p23[1]) * ec.y
                 + bf2f(p23[2]) * ec.z + bf2f(p23[3]) * ec.w;
        float s3 = bf2f(p23[4]) * ec.x + bf2f(p23[5]) * ec.y
                 + bf2f(p23[6]) * ec.z + bf2f(p23[7]) * ec.w;
        if ((j0 + 0 > i) && v4.x) o.x = __logf(s0);
        if ((j0 + 1 > i) && v4.y) o.y = __logf(s1);
        if ((j0 + 2 > i) && v4.z) o.z = __logf(s2);
        if ((j0 + 3 > i) && v4.w) o.w = __logf(s3);
    }
    *(float4*)&out[(size_t)blk * 1024 + j0] = o;
}

// ---------------------------------------------------------------------------
extern "C" void kernel_launch(void* const* d_in, const int* in_sizes, int n_in,
                              void* d_out, int out_size, void* d_ws, size_t ws_size,
                              hipStream_t stream) {
    const float* features = (const float*)d_in[0];
    const int*   vmask    = (const int*)d_in[1];
    const float* Wq       = (const float*)d_in[2];
    const float* bq       = (const float*)d_in[3];
    const float* Wk       = (const float*)d_in[4];
    const float* bk       = (const float*)d_in[5];
    const float* Wg       = (const float*)d_in[6];
    const float* bg       = (const float*)d_in[7];
    float* out = (float*)d_out;

    // ws carve, peak ~97 MB. Pe overlaps Xb+Wt (both dead before k_scores).
    short* Pe = (short*)d_ws;                  // [8][1024][1024][4] bf16 = 67.1 MB
    short* Xb = (short*)d_ws;                  // [8192][1024] bf16 (dead after k_gemm)
    short* Wt = Xb + 8388608;                  // [2048][1024] bf16 (dead after k_gemm)
    short* Qb = Pe + 33554432;                 // [32 bh][1024 i][256 d] bf16 (scaled 1/16)
    short* Kb = Qb + 8388608;                  // [32 bh][1024 j][256 d] bf16
    float* lgA = (float*)(Kb + 8388608);       // [8192][4]
    float* Zp  = lgA + 32768;                  // [4 jt][32 bh][1024 i]
    float* ecT = Zp + 131072;                  // [8192][4]

    k_prep<<<2048, 256, 0, stream>>>(features, Wg, bg, Xb, lgA);
    k_cvt_w<<<dim3(64, 32), dim3(32, 8), 0, stream>>>(Wq, Wk, Wt);
    k_gemm<<<256, 512, 0, stream>>>(Xb, Wt, bq, bk, Qb, Kb);
    k_scores<<<512, 512, 0, stream>>>(Qb, Kb, vmask, Pe, Zp);
    k_c<<<32, 256, 0, stream>>>(lgA, Zp, ecT);
    k_final<<<8192, 256, 0, stream>>>(Pe, vmask, ecT, out);
}